// Round 12
// baseline (198.801 us; speedup 1.0000x reference)
//
#include <hip/hip_runtime.h>
#include <hip/hip_bf16.h>

// Problem constants
#define B_    2
#define S_    1024
#define HID_  1024
#define H_    16
#define P_    2
#define D_    64
#define SV_   2048   // S_*P_
#define NBH_  32     // B_*H_
// SCALE * log2(e) = 0.125 * 1.4426950408889634
#define SCALE_LOG2E 0.18033688f

typedef __attribute__((ext_vector_type(8))) short short8;
typedef __attribute__((ext_vector_type(4))) short short4b;
typedef __attribute__((ext_vector_type(4))) float f32x4;

#if __has_builtin(__builtin_amdgcn_exp2f)
#define EXP2(x) __builtin_amdgcn_exp2f(x)
#else
#define EXP2(x) exp2f(x)
#endif

__device__ __forceinline__ unsigned short f2bf(float f) {
  union { float f; unsigned u; } v; v.f = f;
  unsigned r = v.u + 0x7fffu + ((v.u >> 16) & 1u);
  return (unsigned short)(r >> 16);
}
__device__ __forceinline__ unsigned pack_bf2(float a, float b) {
  __hip_bfloat162 h = __float22bfloat162_rn(make_float2(a, b));
  unsigned u; __builtin_memcpy(&u, &h, 4);
  return u;
}

// ---------------------------------------------------------------------------
// Fused prep kernel (unchanged from round 11).
__global__ __launch_bounds__(256) void prep_kernel(
    const float* __restrict__ x,
    const float* __restrict__ Wq, const float* __restrict__ Wk,
    const float* __restrict__ Wv, const float* __restrict__ Wo,
    const float* __restrict__ aq, const float* __restrict__ ak,
    const float* __restrict__ av, const float* __restrict__ coll,
    unsigned short* __restrict__ Xb, unsigned short* __restrict__ Weff,
    unsigned short* __restrict__ Woeff) {
  __shared__ float shbuf[1536];
  const int bid = blockIdx.x;
  const int tid = threadIdx.x;

  if (bid < 1024) {
    const int n4 = (B_ * S_ * HID_) / 4;
    int i = bid * 256 + tid;
    const int stride = 1024 * 256;
    for (; i < n4; i += stride) {
      float4 v = ((const float4*)x)[i];
      ushort4 o;
      o.x = f2bf(v.x); o.y = f2bf(v.y); o.z = f2bf(v.z); o.w = f2bf(v.w);
      ((ushort4*)Xb)[i] = o;
    }
  } else if (bid < 1216) {
    const int wb = bid - 1024;
    const int d = wb & 63;
    const int t = wb >> 6;
    const float* W = (t == 0) ? Wq : ((t == 1) ? Wk : Wv);
    const float* A = (t == 0) ? aq : ((t == 1) ? ak : av);
    float (*Al)[32] = (float (*)[32])shbuf;
    for (int idx = tid; idx < 512; idx += 256) Al[idx >> 5][idx & 31] = A[idx];
    __syncthreads();
    const int e = tid * 4;
    float wr[16][4];
#pragma unroll
    for (int m = 0; m < 16; ++m) {
      float4 v = *(const float4*)(W + (size_t)(m * 64 + d) * 1024 + e);
      wr[m][0] = v.x; wr[m][1] = v.y; wr[m][2] = v.z; wr[m][3] = v.w;
    }
    for (int hp = 0; hp < 32; ++hp) {
      float acc0 = 0.f, acc1 = 0.f, acc2 = 0.f, acc3 = 0.f;
#pragma unroll
      for (int m = 0; m < 16; ++m) {
        float al = Al[m][hp];
        acc0 += al * wr[m][0]; acc1 += al * wr[m][1];
        acc2 += al * wr[m][2]; acc3 += al * wr[m][3];
      }
      int r = (hp >> 1) * 128 + (hp & 1) * 64 + d;
      ushort4 ov;
      ov.x = f2bf(acc0); ov.y = f2bf(acc1); ov.z = f2bf(acc2); ov.w = f2bf(acc3);
      *(ushort4*)(Weff + ((size_t)t * 2048 + r) * 1024 + e) = ov;
    }
  } else {
    const int f = bid - 1216;
    float* wrow = shbuf;
    float* cl = shbuf + 1024;
    for (int idx = tid; idx < 512; idx += 256) cl[idx] = coll[idx];
    for (int idx = tid; idx < 1024; idx += 256) wrow[idx] = Wo[(size_t)f * 1024 + idx];
    __syncthreads();
    for (int idx = tid; idx < 2048; idx += 256) {
      int o = idx >> 6, d = idx & 63;
      float acc = 0.f;
#pragma unroll
      for (int h = 0; h < 16; ++h) acc += wrow[h * 64 + d] * cl[h * 32 + o];
      Woeff[(size_t)f * 2048 + idx] = f2bf(acc);
    }
  }
}

// ---------------------------------------------------------------------------
// Unified QKV GEMM v2 (unchanged from round 11): 128x128 tile, BK=32,
// triple-buffered, one barrier + counted vmcnt(4) per K-tile, 3 blocks/CU.
__global__ __launch_bounds__(256, 3) void qkv_gemm128(
    const unsigned short* __restrict__ Xb,
    const unsigned short* __restrict__ Weff,
    unsigned short* __restrict__ Qd, unsigned short* __restrict__ Kd,
    unsigned short* __restrict__ Vd) {
  __shared__ unsigned short As[3][128 * 32];   // 24 KB
  __shared__ unsigned short Bs[3][128 * 32];   // 24 KB
  constexpr int K = 1024, NT = 32;              // K / 32
  const int t = threadIdx.x;
  const int wave = t >> 6, lane = t & 63, lq = lane & 15, quad = lane >> 4;
  const int wm = wave >> 1, wn = wave & 1;      // 2x2 waves, 64x64 each
  const int z = blockIdx.z;
  const int row0 = blockIdx.x * 128, col0 = blockIdx.y * 128;
  const unsigned short* Ap = (z == 2) ? (Weff + (size_t)2 * 2048 * 1024) : Xb;
  const unsigned short* Bp = (z == 2) ? Xb : (Weff + (size_t)z * 2048 * 1024);

  const int srow = lane >> 2;                       // 0..15
  const int sgr = (lane & 3) ^ ((lane >> 3) & 3);   // pre-swizzled granule

  auto stage = [&](int kt, int buf) {
#pragma unroll
    for (int j = 0; j < 2; ++j) {
      const int rloc = wave * 32 + j * 16;  // wave-uniform chunk base row
      const unsigned short* ga =
          Ap + (size_t)(row0 + rloc + srow) * K + kt * 32 + sgr * 8;
      __builtin_amdgcn_global_load_lds(
          (const __attribute__((address_space(1))) unsigned int*)ga,
          (__attribute__((address_space(3))) unsigned int*)(&As[buf][rloc * 32]),
          16, 0, 0);
      const unsigned short* gb =
          Bp + (size_t)(col0 + rloc + srow) * K + kt * 32 + sgr * 8;
      __builtin_amdgcn_global_load_lds(
          (const __attribute__((address_space(1))) unsigned int*)gb,
          (__attribute__((address_space(3))) unsigned int*)(&Bs[buf][rloc * 32]),
          16, 0, 0);
    }
  };

  f32x4 acc[4][4];
#pragma unroll
  for (int mi = 0; mi < 4; ++mi)
#pragma unroll
    for (int ni = 0; ni < 4; ++ni) acc[mi][ni] = (f32x4){0.f, 0.f, 0.f, 0.f};

  stage(0, 0);
  stage(1, 1);

  const int swz4 = (lq >> 1) & 3;   // read-side granule XOR

  for (int kt = 0; kt < NT; ++kt) {
    const int buf = kt % 3;
    if (kt + 1 < NT) {
      asm volatile("s_waitcnt vmcnt(4)" ::: "memory");
    } else {
      asm volatile("s_waitcnt vmcnt(0)" ::: "memory");
    }
    asm volatile("s_barrier" ::: "memory");
    if (kt + 2 < NT) stage(kt + 2, (kt + 2) % 3);  // overwrites (kt-1)%3

    const unsigned short* __restrict__ Ab = &As[buf][0];
    const unsigned short* __restrict__ Bb = &Bs[buf][0];
    short8 af[4], bf[4];
#pragma unroll
    for (int mi = 0; mi < 4; ++mi)
      af[mi] = *(const short8*)(
          Ab + (wm * 64 + mi * 16 + lq) * 32 + ((quad ^ swz4) * 8));
#pragma unroll
    for (int ni = 0; ni < 4; ++ni)
      bf[ni] = *(const short8*)(
          Bb + (wn * 64 + ni * 16 + lq) * 32 + ((quad ^ swz4) * 8));
    __builtin_amdgcn_s_setprio(1);
#pragma unroll
    for (int mi = 0; mi < 4; ++mi)
#pragma unroll
      for (int ni = 0; ni < 4; ++ni)
        acc[mi][ni] = __builtin_amdgcn_mfma_f32_16x16x32_bf16(
            af[mi], bf[ni], acc[mi][ni], 0, 0, 0);
    __builtin_amdgcn_s_setprio(0);
  }

  // Epilogue: scattered bf16 stores into head-interleaved layouts.
#pragma unroll
  for (int mi = 0; mi < 4; ++mi) {
#pragma unroll
    for (int ni = 0; ni < 4; ++ni) {
#pragma unroll
      for (int i = 0; i < 4; ++i) {
        int grow = row0 + wm * 64 + mi * 16 + quad * 4 + i;
        int gcol = col0 + wn * 64 + ni * 16 + lq;
        float val = acc[mi][ni][i];
        if (z != 2) {
          if (z == 0) val *= SCALE_LOG2E;  // pre-scale Q for exp2-direct attn
          int b = grow >> 10, n = grow & 1023;
          int h = gcol >> 7, p = (gcol >> 6) & 1, d = gcol & 63;
          unsigned short* dst = (z == 0) ? Qd : Kd;
          dst[((size_t)((b * 16 + h) * 2048) + n * 2 + p) * 64 + d] = f2bf(val);
        } else {
          // grow = (h,p,d), gcol = (b, n)
          int h = grow >> 7, p = (grow >> 6) & 1, d = grow & 63;
          int b = gcol >> 10, n = gcol & 1023;
          Vd[((size_t)((b * 16 + h) * 64 + d)) * 2048 + n * 2 + p] = f2bf(val);
        }
      }
    }
  }
}

// ---------------------------------------------------------------------------
// Output GEMM (unchanged from round 11).
__global__ __launch_bounds__(256) void gemm64p(
    const unsigned short* __restrict__ A,      // [2048 x 2048] row-major
    const unsigned short* __restrict__ Bbase,  // [1024 x 2048] (B^T form)
    float* __restrict__ Cf) {                  // [2048 x 1024]
  __shared__ unsigned short As[3][64 * 64];    // 24 KB
  __shared__ unsigned short Bs[3][64 * 64];    // 24 KB
  constexpr int K = 2048, N = 1024, NT = 32;   // K / 64
  const int t = threadIdx.x;
  const int wave = t >> 6, lane = t & 63, lrow = lane & 15, quad = lane >> 4;
  const int wm = wave >> 1, wn = wave & 1;     // 2x2 wave grid, 32x32 each
  const int row0 = blockIdx.x * 64, col0 = blockIdx.y * 64;
  const int srow8 = lane >> 3;
  const int sslot = (lane & 7) ^ srow8;        // pre-swizzled global slot
  const int swz = lrow & 7;

  auto stage = [&](int kt, int buf) {
#pragma unroll
    for (int j = 0; j < 2; ++j) {
      const int rloc = wave * 16 + j * 8;
      const unsigned short* ga =
          A + (size_t)(row0 + rloc + srow8) * K + kt * 64 + sslot * 8;
      __builtin_amdgcn_global_load_lds(
          (const __attribute__((address_space(1))) unsigned int*)ga,
          (__attribute__((address_space(3))) unsigned int*)(&As[buf][rloc * 64]),
          16, 0, 0);
      const unsigned short* gb =
          Bbase + (size_t)(col0 + rloc + srow8) * K + kt * 64 + sslot * 8;
      __builtin_amdgcn_global_load_lds(
          (const __attribute__((address_space(1))) unsigned int*)gb,
          (__attribute__((address_space(3))) unsigned int*)(&Bs[buf][rloc * 64]),
          16, 0, 0);
    }
  };

  f32x4 acc[2][2];
#pragma unroll
  for (int mi = 0; mi < 2; ++mi)
#pragma unroll
    for (int ni = 0; ni < 2; ++ni) acc[mi][ni] = (f32x4){0.f, 0.f, 0.f, 0.f};

  stage(0, 0);
  stage(1, 1);

  for (int kt = 0; kt < NT; ++kt) {
    const int buf = kt % 3;
    if (kt < NT - 1) {
      asm volatile("s_waitcnt vmcnt(4)" ::: "memory");  // tile kt landed
    } else {
      asm volatile("s_waitcnt vmcnt(0)" ::: "memory");
    }
    asm volatile("s_barrier" ::: "memory");
    if (kt + 2 < NT) stage(kt + 2, (kt + 2) % 3);

    const unsigned short* __restrict__ Ab = &As[buf][0];
    const unsigned short* __restrict__ Bb = &Bs[buf][0];
    short8 af[2][2], bf[2][2];
#pragma unroll
    for (int mi = 0; mi < 2; ++mi)
#pragma unroll
      for (int ks = 0; ks < 2; ++ks)
        af[mi][ks] = *(const short8*)(
            Ab + (wm * 32 + mi * 16 + lrow) * 64 + (((ks * 4 + quad) ^ swz) * 8));
#pragma unroll
    for (int ni = 0; ni < 2; ++ni)
#pragma unroll
      for (int ks = 0; ks < 2; ++ks)
        bf[ni][ks] = *(const short8*)(
            Bb + (wn * 32 + ni * 16 + lrow) * 64 + (((ks * 4 + quad) ^ swz) * 8));
    __builtin_amdgcn_s_setprio(1);
#pragma unroll
    for (int mi = 0; mi < 2; ++mi)
#pragma unroll
      for (int ni = 0; ni < 2; ++ni) {
        acc[mi][ni] = __builtin_amdgcn_mfma_f32_16x16x32_bf16(
            af[mi][0], bf[ni][0], acc[mi][ni], 0, 0, 0);
        acc[mi][ni] = __builtin_amdgcn_mfma_f32_16x16x32_bf16(
            af[mi][1], bf[ni][1], acc[mi][ni], 0, 0, 0);
      }
    __builtin_amdgcn_s_setprio(0);
  }

#pragma unroll
  for (int mi = 0; mi < 2; ++mi)
#pragma unroll
    for (int ni = 0; ni < 2; ++ni)
#pragma unroll
      for (int i = 0; i < 4; ++i) {
        int grow = row0 + wm * 32 + mi * 16 + quad * 4 + i;
        int gcol = col0 + wn * 32 + ni * 16 + lrow;
        Cf[(size_t)grow * N + gcol] = acc[mi][ni][i];
      }
}

// ---------------------------------------------------------------------------
// Causal flash attention v7: QBLK=128 per block (each wave owns TWO 16-row
// q-groups: rows qt*128 + w*16 + lq and +64). Same KVBLK=64 triple-buffer
// one-barrier staging as v6, but every tile now feeds 2x the MFMA work and
// the ka fragments are shared by both groups (LDS reads per MFMA halve).
// Causality exact, zero wasted FLOPs: group0 full for kt<2qt, diag at
// kt==2qt, SKIPPED (wave-uniform) at kt==2qt+1; group1 full until diag at
// kt==2qt+1. Grid (32 bh, 16): qt = y<8 ? y : 23-y pairs CU-co-resident
// blocks (y, y+8) to a uniform 34 tiles. 2 blocks/CU.
__global__ __launch_bounds__(256, 2) void attn_kernel(
    const unsigned short* __restrict__ Qv, const unsigned short* __restrict__ Kv,
    const unsigned short* __restrict__ Vt, unsigned short* __restrict__ Aov) {
  __shared__ unsigned short Ks[3][4096];   // [buf][row 64][col 64] swizzled
  __shared__ unsigned short Vs[3][4096];   // [buf][d 64][kcol 64] swizzled
  const int bh = blockIdx.x;
  const int yy = blockIdx.y;
  const int qt = (yy < 8) ? yy : (23 - yy);   // 0..15
  const int t = threadIdx.x;
  const int w = t >> 6, lane = t & 63, lq = lane & 15, quad = lane >> 4;
  const int l3 = lq & 7;

  const unsigned short* Qh = Qv + (size_t)bh * SV_ * D_;
  const unsigned short* Kh = Kv + (size_t)bh * SV_ * D_;
  const unsigned short* Vh = Vt + (size_t)bh * D_ * SV_;

  const int qrow0 = qt * 128 + w * 16 + lq;   // group0 q row
  const int qrow1 = qrow0 + 64;               // group1 q row
  short8 bq0_0 = *(const short8*)(Qh + (size_t)qrow0 * 64 + quad * 8);
  short8 bq1_0 = *(const short8*)(Qh + (size_t)qrow0 * 64 + 32 + quad * 8);
  short8 bq0_1 = *(const short8*)(Qh + (size_t)qrow1 * 64 + quad * 8);
  short8 bq1_1 = *(const short8*)(Qh + (size_t)qrow1 * 64 + 32 + quad * 8);

  // Staging: lane-linear LDS granules; global side applies the XOR swizzle.
  const int sg = (lane & 7) ^ ((lane >> 3) & 7);  // granule ^ (row&7)
  const int r0 = w * 16 + (lane >> 3);            // row for issue 0 (+8 for issue 1)
  const unsigned short* Kg0 = Kh + r0 * 64 + sg * 8;
  const unsigned short* Vg0 = Vh + (size_t)r0 * SV_ + sg * 8;
  const int lds0 = w * 1024;       // shorts (16 rows x 64), wave-uniform
  const int lds1 = lds0 + 512;     // +8 rows

  auto stage = [&](int kt) {
    const int buf = kt % 3;
    const unsigned short* kg = Kg0 + kt * 4096;
    const unsigned short* vg = Vg0 + kt * 64;
    __builtin_amdgcn_global_load_lds(
        (const __attribute__((address_space(1))) unsigned int*)kg,
        (__attribute__((address_space(3))) unsigned int*)(&Ks[buf][lds0]), 16, 0, 0);
    __builtin_amdgcn_global_load_lds(
        (const __attribute__((address_space(1))) unsigned int*)(kg + 8 * 64),
        (__attribute__((address_space(3))) unsigned int*)(&Ks[buf][lds1]), 16, 0, 0);
    __builtin_amdgcn_global_load_lds(
        (const __attribute__((address_space(1))) unsigned int*)vg,
        (__attribute__((address_space(3))) unsigned int*)(&Vs[buf][lds0]), 16, 0, 0);
    __builtin_amdgcn_global_load_lds(
        (const __attribute__((address_space(1))) unsigned int*)(vg + (size_t)8 * SV_),
        (__attribute__((address_space(3))) unsigned int*)(&Vs[buf][lds1]), 16, 0, 0);
  };

  float l_sum0 = 0.f, l_sum1 = 0.f;
  f32x4 o_acc0[4], o_acc1[4];
#pragma unroll
  for (int nd = 0; nd < 4; ++nd) {
    o_acc0[nd] = (f32x4){0.f, 0.f, 0.f, 0.f};
    o_acc1[nd] = (f32x4){0.f, 0.f, 0.f, 0.f};
  }

  const int nt = 2 * qt + 2;
  stage(0);
  stage(1);

  for (int kt = 0; kt < nt; ++kt) {
    const int buf = kt % 3;
    if (kt + 1 < nt) {
      asm volatile("s_waitcnt vmcnt(4)" ::: "memory");
    } else {
      asm volatile("s_waitcnt vmcnt(0)" ::: "memory");
    }
    asm volatile("s_barrier" ::: "memory");
    if (kt + 2 < nt) stage(kt + 2);   // overwrites buf (kt-1)%3: safe now

    // ---- K fragments from LDS (shared by both q-groups) ----
    const unsigned short* Kb = Ks[buf];
    short8 ka[4][2];
#pragma unroll
    for (int t4 = 0; t4 < 4; ++t4)
#pragma unroll
      for (int c = 0; c < 2; ++c)
        ka[t4][c] = *(const short8*)(Kb + (t4 * 16 + lq) * 64 + (((c * 4 + quad) ^ l3) * 8));

    const unsigned short* Vb = Vs[buf];
    const int kc0 = kt * 64 + quad * 4;
    __builtin_amdgcn_s_setprio(1);

    // ======== group 0 (rows qt*128 .. +64): active for kt <= 2qt ========
    if (kt <= 2 * qt) {
      f32x4 s[4];
#pragma unroll
      for (int t4 = 0; t4 < 4; ++t4) {
        f32x4 zz = (f32x4){0.f, 0.f, 0.f, 0.f};
        zz = __builtin_amdgcn_mfma_f32_16x16x32_bf16(ka[t4][0], bq0_0, zz, 0, 0, 0);
        s[t4] = __builtin_amdgcn_mfma_f32_16x16x32_bf16(ka[t4][1], bq1_0, zz, 0, 0, 0);
      }
      const bool diag = (kt == 2 * qt);
      float rs = 0.f;
#pragma unroll
      for (int t4 = 0; t4 < 4; ++t4) {
        float p0 = EXP2(s[t4][0]), p1 = EXP2(s[t4][1]);
        float p2 = EXP2(s[t4][2]), p3 = EXP2(s[t4][3]);
        if (diag) {
          const int kc = kc0 + t4 * 16;
          if (kc + 0 > qrow0) p0 = 0.f;
          if (kc + 1 > qrow0) p1 = 0.f;
          if (kc + 2 > qrow0) p2 = 0.f;
          if (kc + 3 > qrow0) p3 = 0.f;
        }
        rs += (p0 + p1) + (p2 + p3);
        unsigned ww[2];
        ww[0] = pack_bf2(p0, p1);
        ww[1] = pack_bf2(p2, p3);
        short4b pb;
        __builtin_memcpy(&pb, ww, 8);
        const int cg = t4 * 2 + (quad >> 1);
        const int vcol = ((cg ^ l3) * 8) + (quad & 1) * 4;
#pragma unroll
        for (int nd = 0; nd < 4; ++nd) {
          short4b va4;
          __builtin_memcpy(&va4, Vb + (nd * 16 + lq) * 64 + vcol, 8);
          o_acc0[nd] = __builtin_amdgcn_mfma_f32_16x16x16bf16_1k(va4, pb,
                                                                 o_acc0[nd], 0, 0, 0);
        }
      }
      l_sum0 += rs;
    }

    // ======== group 1 (rows qt*128+64 .. +128): active for all kt ========
    {
      f32x4 s[4];
#pragma unroll
      for (int t4 = 0; t4 < 4; ++t4) {
        f32x4 zz = (f32x4){0.f, 0.f, 0.f, 0.f};
        zz = __builtin_amdgcn_mfma_f32_16x16x32_bf16(ka[t4][0], bq0_1, zz, 0, 0, 0);
        s[t4] = __builtin_amdgcn_mfma_f32_16x16x32_bf16(ka[t4][1], bq1_1, zz, 0, 0, 0);
      }
      const bool diag = (kt == 2 * qt + 1);
      float rs = 0.f;
#pragma unroll
      for (int t4 = 0; t4 < 4; ++t4) {
        float p0 = EXP2(s[t4][0]), p1 = EXP2(s[t4][1]);
        float p2 = EXP2(s[t4][2]), p3 = EXP2(s[t4][3]);
        if (diag) {
          const int kc = kc0 + t4 * 16;
          if (kc + 0 > qrow1) p0 = 0.f;
          if (kc + 1 > qrow1) p1 = 0.f;
          if (kc + 2 > qrow1) p2 = 0.f;
          if (kc + 3 > qrow1) p3 = 0.f;
        }
        rs += (p0 + p1) + (p2 + p3);
        unsigned ww[2];
        ww[0] = pack_bf2(p0, p1);
        ww[1] = pack_bf2(p2, p3);
        short4b pb;
        __builtin_memcpy(&pb, ww, 8);
        const int cg = t4 * 2 + (quad >> 1);
        const int vcol = ((cg ^ l3) * 8) + (quad & 1) * 4;
#pragma unroll
        for (int nd = 0; nd < 4; ++nd) {
          short4b va4;
          __builtin_memcpy(&va4, Vb + (nd * 16 + lq) * 64 + vcol, 8);
          o_acc1[nd] = __builtin_amdgcn_mfma_f32_16x16x16bf16_1k(va4, pb,
                                                                 o_acc1[nd], 0, 0, 0);
        }
      }
      l_sum1 += rs;
    }

    __builtin_amdgcn_s_setprio(0);
  }

  // final cross-quad row-sum reductions
  l_sum0 += __shfl_xor(l_sum0, 16);
  l_sum0 += __shfl_xor(l_sum0, 32);
  l_sum1 += __shfl_xor(l_sum1, 16);
  l_sum1 += __shfl_xor(l_sum1, 32);

  const int b = bh >> 4, h = bh & 15;
  {
    const float inv = 1.0f / l_sum0;
    const int n = qrow0 >> 1, p = qrow0 & 1;
    unsigned short* dst = Aov + ((size_t)(b * 1024 + n)) * 2048 + (h * 2 + p) * 64;
#pragma unroll
    for (int nd = 0; nd < 4; ++nd) {
      uint2 dw;
      dw.x = pack_bf2(o_acc0[nd][0] * inv, o_acc0[nd][1] * inv);
      dw.y = pack_bf2(o_acc0[nd][2] * inv, o_acc0[nd][3] * inv);
      *(uint2*)(dst + nd * 16 + quad * 4) = dw;
    }
  }
  {
    const float inv = 1.0f / l_sum1;
    const int n = qrow1 >> 1, p = qrow1 & 1;
    unsigned short* dst = Aov + ((size_t)(b * 1024 + n)) * 2048 + (h * 2 + p) * 64;
#pragma unroll
    for (int nd = 0; nd < 4; ++nd) {
      uint2 dw;
      dw.x = pack_bf2(o_acc1[nd][0] * inv, o_acc1[nd][1] * inv);
      dw.y = pack_bf2(o_acc1[nd][2] * inv, o_acc1[nd][3] * inv);
      *(uint2*)(dst + nd * 16 + quad * 4) = dw;
    }
  }
}

// ---------------------------------------------------------------------------
extern "C" void kernel_launch(void* const* d_in, const int* in_sizes, int n_in,
                              void* d_out, int out_size, void* d_ws, size_t ws_size,
                              hipStream_t stream) {
  (void)in_sizes; (void)n_in; (void)out_size; (void)ws_size;
  const float* x    = (const float*)d_in[0];
  const float* Wq   = (const float*)d_in[1];
  const float* Wk   = (const float*)d_in[2];
  const float* Wv   = (const float*)d_in[3];
  const float* Wo   = (const float*)d_in[4];
  const float* aq   = (const float*)d_in[5];
  const float* ak   = (const float*)d_in[6];
  const float* av   = (const float*)d_in[7];
  const float* coll = (const float*)d_in[8];
  float* out = (float*)d_out;

  char* ws = (char*)d_ws;
  const size_t MB = 1024 * 1024;
  unsigned short* Xb    = (unsigned short*)(ws);            // 4 MB  [0,4)
  unsigned short* Woeff = (unsigned short*)(ws + 4 * MB);   // 4 MB  [4,8)
  unsigned short* Weff  = (unsigned short*)(ws + 8 * MB);   // 12 MB [8,20)
  unsigned short* Qv    = (unsigned short*)(ws + 20 * MB);  // 8 MB  [20,28)
  unsigned short* Kv    = (unsigned short*)(ws + 28 * MB);  // 8 MB  [28,36)
  unsigned short* Vt    = (unsigned short*)(ws + 36 * MB);  // 8 MB  [36,44)
  // Weff dead after QKV GEMM; reuse:
  unsigned short* Aov   = (unsigned short*)(ws + 8 * MB);   // 8 MB  [8,16)

  prep_kernel<<<dim3(2240), dim3(256), 0, stream>>>(
      x, Wq, Wk, Wv, Wo, aq, ak, av, coll, Xb, Weff, Woeff);
  qkv_gemm128<<<dim3(16, 16, 3), dim3(256), 0, stream>>>(Xb, Weff, Qv, Kv, Vt);
  attn_kernel<<<dim3(32, 16), dim3(256), 0, stream>>>(Qv, Kv, Vt, Aov);
  gemm64p<<<dim3(32, 16), dim3(256), 0, stream>>>(Aov, Woeff, out);
}

// Round 13
// 186.851 us; speedup vs baseline: 1.0640x; 1.0640x over previous
//
#include <hip/hip_runtime.h>
#include <hip/hip_bf16.h>

// Problem constants
#define B_    2
#define S_    1024
#define HID_  1024
#define H_    16
#define P_    2
#define D_    64
#define SV_   2048   // S_*P_
#define NBH_  32     // B_*H_
// SCALE * log2(e) = 0.125 * 1.4426950408889634
#define SCALE_LOG2E 0.18033688f

typedef __attribute__((ext_vector_type(8))) short short8;
typedef __attribute__((ext_vector_type(4))) short short4b;
typedef __attribute__((ext_vector_type(4))) float f32x4;

#if __has_builtin(__builtin_amdgcn_exp2f)
#define EXP2(x) __builtin_amdgcn_exp2f(x)
#else
#define EXP2(x) exp2f(x)
#endif

__device__ __forceinline__ unsigned short f2bf(float f) {
  union { float f; unsigned u; } v; v.f = f;
  unsigned r = v.u + 0x7fffu + ((v.u >> 16) & 1u);
  return (unsigned short)(r >> 16);
}
__device__ __forceinline__ unsigned pack_bf2(float a, float b) {
  __hip_bfloat162 h = __float22bfloat162_rn(make_float2(a, b));
  unsigned u; __builtin_memcpy(&u, &h, 4);
  return u;
}

// ---------------------------------------------------------------------------
// Fused prep kernel (unchanged from round 11).
__global__ __launch_bounds__(256) void prep_kernel(
    const float* __restrict__ x,
    const float* __restrict__ Wq, const float* __restrict__ Wk,
    const float* __restrict__ Wv, const float* __restrict__ Wo,
    const float* __restrict__ aq, const float* __restrict__ ak,
    const float* __restrict__ av, const float* __restrict__ coll,
    unsigned short* __restrict__ Xb, unsigned short* __restrict__ Weff,
    unsigned short* __restrict__ Woeff) {
  __shared__ float shbuf[1536];
  const int bid = blockIdx.x;
  const int tid = threadIdx.x;

  if (bid < 1024) {
    const int n4 = (B_ * S_ * HID_) / 4;
    int i = bid * 256 + tid;
    const int stride = 1024 * 256;
    for (; i < n4; i += stride) {
      float4 v = ((const float4*)x)[i];
      ushort4 o;
      o.x = f2bf(v.x); o.y = f2bf(v.y); o.z = f2bf(v.z); o.w = f2bf(v.w);
      ((ushort4*)Xb)[i] = o;
    }
  } else if (bid < 1216) {
    const int wb = bid - 1024;
    const int d = wb & 63;
    const int t = wb >> 6;
    const float* W = (t == 0) ? Wq : ((t == 1) ? Wk : Wv);
    const float* A = (t == 0) ? aq : ((t == 1) ? ak : av);
    float (*Al)[32] = (float (*)[32])shbuf;
    for (int idx = tid; idx < 512; idx += 256) Al[idx >> 5][idx & 31] = A[idx];
    __syncthreads();
    const int e = tid * 4;
    float wr[16][4];
#pragma unroll
    for (int m = 0; m < 16; ++m) {
      float4 v = *(const float4*)(W + (size_t)(m * 64 + d) * 1024 + e);
      wr[m][0] = v.x; wr[m][1] = v.y; wr[m][2] = v.z; wr[m][3] = v.w;
    }
    for (int hp = 0; hp < 32; ++hp) {
      float acc0 = 0.f, acc1 = 0.f, acc2 = 0.f, acc3 = 0.f;
#pragma unroll
      for (int m = 0; m < 16; ++m) {
        float al = Al[m][hp];
        acc0 += al * wr[m][0]; acc1 += al * wr[m][1];
        acc2 += al * wr[m][2]; acc3 += al * wr[m][3];
      }
      int r = (hp >> 1) * 128 + (hp & 1) * 64 + d;
      ushort4 ov;
      ov.x = f2bf(acc0); ov.y = f2bf(acc1); ov.z = f2bf(acc2); ov.w = f2bf(acc3);
      *(ushort4*)(Weff + ((size_t)t * 2048 + r) * 1024 + e) = ov;
    }
  } else {
    const int f = bid - 1216;
    float* wrow = shbuf;
    float* cl = shbuf + 1024;
    for (int idx = tid; idx < 512; idx += 256) cl[idx] = coll[idx];
    for (int idx = tid; idx < 1024; idx += 256) wrow[idx] = Wo[(size_t)f * 1024 + idx];
    __syncthreads();
    for (int idx = tid; idx < 2048; idx += 256) {
      int o = idx >> 6, d = idx & 63;
      float acc = 0.f;
#pragma unroll
      for (int h = 0; h < 16; ++h) acc += wrow[h * 64 + d] * cl[h * 32 + o];
      Woeff[(size_t)f * 2048 + idx] = f2bf(acc);
    }
  }
}

// ---------------------------------------------------------------------------
// Unified QKV GEMM v2 (unchanged): 128x128 tile, BK=32, triple-buffered,
// one barrier + counted vmcnt(4) per K-tile, 3 blocks/CU.
__global__ __launch_bounds__(256, 3) void qkv_gemm128(
    const unsigned short* __restrict__ Xb,
    const unsigned short* __restrict__ Weff,
    unsigned short* __restrict__ Qd, unsigned short* __restrict__ Kd,
    unsigned short* __restrict__ Vd) {
  __shared__ unsigned short As[3][128 * 32];   // 24 KB
  __shared__ unsigned short Bs[3][128 * 32];   // 24 KB
  constexpr int K = 1024, NT = 32;              // K / 32
  const int t = threadIdx.x;
  const int wave = t >> 6, lane = t & 63, lq = lane & 15, quad = lane >> 4;
  const int wm = wave >> 1, wn = wave & 1;      // 2x2 waves, 64x64 each
  const int z = blockIdx.z;
  const int row0 = blockIdx.x * 128, col0 = blockIdx.y * 128;
  const unsigned short* Ap = (z == 2) ? (Weff + (size_t)2 * 2048 * 1024) : Xb;
  const unsigned short* Bp = (z == 2) ? Xb : (Weff + (size_t)z * 2048 * 1024);

  const int srow = lane >> 2;                       // 0..15
  const int sgr = (lane & 3) ^ ((lane >> 3) & 3);   // pre-swizzled granule

  auto stage = [&](int kt, int buf) {
#pragma unroll
    for (int j = 0; j < 2; ++j) {
      const int rloc = wave * 32 + j * 16;  // wave-uniform chunk base row
      const unsigned short* ga =
          Ap + (size_t)(row0 + rloc + srow) * K + kt * 32 + sgr * 8;
      __builtin_amdgcn_global_load_lds(
          (const __attribute__((address_space(1))) unsigned int*)ga,
          (__attribute__((address_space(3))) unsigned int*)(&As[buf][rloc * 32]),
          16, 0, 0);
      const unsigned short* gb =
          Bp + (size_t)(col0 + rloc + srow) * K + kt * 32 + sgr * 8;
      __builtin_amdgcn_global_load_lds(
          (const __attribute__((address_space(1))) unsigned int*)gb,
          (__attribute__((address_space(3))) unsigned int*)(&Bs[buf][rloc * 32]),
          16, 0, 0);
    }
  };

  f32x4 acc[4][4];
#pragma unroll
  for (int mi = 0; mi < 4; ++mi)
#pragma unroll
    for (int ni = 0; ni < 4; ++ni) acc[mi][ni] = (f32x4){0.f, 0.f, 0.f, 0.f};

  stage(0, 0);
  stage(1, 1);

  const int swz4 = (lq >> 1) & 3;   // read-side granule XOR

  for (int kt = 0; kt < NT; ++kt) {
    const int buf = kt % 3;
    if (kt + 1 < NT) {
      asm volatile("s_waitcnt vmcnt(4)" ::: "memory");
    } else {
      asm volatile("s_waitcnt vmcnt(0)" ::: "memory");
    }
    asm volatile("s_barrier" ::: "memory");
    if (kt + 2 < NT) stage(kt + 2, (kt + 2) % 3);  // overwrites (kt-1)%3

    const unsigned short* __restrict__ Ab = &As[buf][0];
    const unsigned short* __restrict__ Bb = &Bs[buf][0];
    short8 af[4], bf[4];
#pragma unroll
    for (int mi = 0; mi < 4; ++mi)
      af[mi] = *(const short8*)(
          Ab + (wm * 64 + mi * 16 + lq) * 32 + ((quad ^ swz4) * 8));
#pragma unroll
    for (int ni = 0; ni < 4; ++ni)
      bf[ni] = *(const short8*)(
          Bb + (wn * 64 + ni * 16 + lq) * 32 + ((quad ^ swz4) * 8));
    __builtin_amdgcn_s_setprio(1);
#pragma unroll
    for (int mi = 0; mi < 4; ++mi)
#pragma unroll
      for (int ni = 0; ni < 4; ++ni)
        acc[mi][ni] = __builtin_amdgcn_mfma_f32_16x16x32_bf16(
            af[mi], bf[ni], acc[mi][ni], 0, 0, 0);
    __builtin_amdgcn_s_setprio(0);
  }

  // Epilogue: scattered bf16 stores into head-interleaved layouts.
#pragma unroll
  for (int mi = 0; mi < 4; ++mi) {
#pragma unroll
    for (int ni = 0; ni < 4; ++ni) {
#pragma unroll
      for (int i = 0; i < 4; ++i) {
        int grow = row0 + wm * 64 + mi * 16 + quad * 4 + i;
        int gcol = col0 + wn * 64 + ni * 16 + lq;
        float val = acc[mi][ni][i];
        if (z != 2) {
          if (z == 0) val *= SCALE_LOG2E;  // pre-scale Q for exp2-direct attn
          int b = grow >> 10, n = grow & 1023;
          int h = gcol >> 7, p = (gcol >> 6) & 1, d = gcol & 63;
          unsigned short* dst = (z == 0) ? Qd : Kd;
          dst[((size_t)((b * 16 + h) * 2048) + n * 2 + p) * 64 + d] = f2bf(val);
        } else {
          // grow = (h,p,d), gcol = (b, n)
          int h = grow >> 7, p = (grow >> 6) & 1, d = grow & 63;
          int b = gcol >> 10, n = gcol & 1023;
          Vd[((size_t)((b * 16 + h) * 64 + d)) * 2048 + n * 2 + p] = f2bf(val);
        }
      }
    }
  }
}

// ---------------------------------------------------------------------------
// Output GEMM (unchanged): 64x64 tile, BK=64, triple-buffered, one barrier
// + counted vmcnt(4) per K-tile. Grid (32,16) = 2 blocks/CU.
__global__ __launch_bounds__(256) void gemm64p(
    const unsigned short* __restrict__ A,      // [2048 x 2048] row-major
    const unsigned short* __restrict__ Bbase,  // [1024 x 2048] (B^T form)
    float* __restrict__ Cf) {                  // [2048 x 1024]
  __shared__ unsigned short As[3][64 * 64];    // 24 KB
  __shared__ unsigned short Bs[3][64 * 64];    // 24 KB
  constexpr int K = 2048, N = 1024, NT = 32;   // K / 64
  const int t = threadIdx.x;
  const int wave = t >> 6, lane = t & 63, lrow = lane & 15, quad = lane >> 4;
  const int wm = wave >> 1, wn = wave & 1;     // 2x2 wave grid, 32x32 each
  const int row0 = blockIdx.x * 64, col0 = blockIdx.y * 64;
  const int srow8 = lane >> 3;
  const int sslot = (lane & 7) ^ srow8;        // pre-swizzled global slot
  const int swz = lrow & 7;

  auto stage = [&](int kt, int buf) {
#pragma unroll
    for (int j = 0; j < 2; ++j) {
      const int rloc = wave * 16 + j * 8;
      const unsigned short* ga =
          A + (size_t)(row0 + rloc + srow8) * K + kt * 64 + sslot * 8;
      __builtin_amdgcn_global_load_lds(
          (const __attribute__((address_space(1))) unsigned int*)ga,
          (__attribute__((address_space(3))) unsigned int*)(&As[buf][rloc * 64]),
          16, 0, 0);
      const unsigned short* gb =
          Bbase + (size_t)(col0 + rloc + srow8) * K + kt * 64 + sslot * 8;
      __builtin_amdgcn_global_load_lds(
          (const __attribute__((address_space(1))) unsigned int*)gb,
          (__attribute__((address_space(3))) unsigned int*)(&Bs[buf][rloc * 64]),
          16, 0, 0);
    }
  };

  f32x4 acc[2][2];
#pragma unroll
  for (int mi = 0; mi < 2; ++mi)
#pragma unroll
    for (int ni = 0; ni < 2; ++ni) acc[mi][ni] = (f32x4){0.f, 0.f, 0.f, 0.f};

  stage(0, 0);
  stage(1, 1);

  for (int kt = 0; kt < NT; ++kt) {
    const int buf = kt % 3;
    if (kt < NT - 1) {
      asm volatile("s_waitcnt vmcnt(4)" ::: "memory");  // tile kt landed
    } else {
      asm volatile("s_waitcnt vmcnt(0)" ::: "memory");
    }
    asm volatile("s_barrier" ::: "memory");
    if (kt + 2 < NT) stage(kt + 2, (kt + 2) % 3);

    const unsigned short* __restrict__ Ab = &As[buf][0];
    const unsigned short* __restrict__ Bb = &Bs[buf][0];
    short8 af[2][2], bf[2][2];
#pragma unroll
    for (int mi = 0; mi < 2; ++mi)
#pragma unroll
      for (int ks = 0; ks < 2; ++ks)
        af[mi][ks] = *(const short8*)(
            Ab + (wm * 32 + mi * 16 + lrow) * 64 + (((ks * 4 + quad) ^ swz) * 8));
#pragma unroll
    for (int ni = 0; ni < 2; ++ni)
#pragma unroll
      for (int ks = 0; ks < 2; ++ks)
        bf[ni][ks] = *(const short8*)(
            Bb + (wn * 32 + ni * 16 + lrow) * 64 + (((ks * 4 + quad) ^ swz) * 8));
    __builtin_amdgcn_s_setprio(1);
#pragma unroll
    for (int mi = 0; mi < 2; ++mi)
#pragma unroll
      for (int ni = 0; ni < 2; ++ni) {
        acc[mi][ni] = __builtin_amdgcn_mfma_f32_16x16x32_bf16(
            af[mi][0], bf[ni][0], acc[mi][ni], 0, 0, 0);
        acc[mi][ni] = __builtin_amdgcn_mfma_f32_16x16x32_bf16(
            af[mi][1], bf[ni][1], acc[mi][ni], 0, 0, 0);
      }
    __builtin_amdgcn_s_setprio(0);
  }

#pragma unroll
  for (int mi = 0; mi < 2; ++mi)
#pragma unroll
    for (int ni = 0; ni < 2; ++ni)
#pragma unroll
      for (int i = 0; i < 4; ++i) {
        int grow = row0 + wm * 32 + mi * 16 + quad * 4 + i;
        int gcol = col0 + wn * 32 + ni * 16 + lrow;
        Cf[(size_t)grow * N + gcol] = acc[mi][ni][i];
      }
}

// ---------------------------------------------------------------------------
// Causal flash attention v6b: identical per-row math/structure to v6
// (global_load_lds staging, KVBLK=64, triple-buffered K/V 48 KB -> 3
// blocks/CU, one barrier + one counted vmcnt per tile, in-register P via
// 16x16x16 MFMA, Q pre-scaled) with LONGEST-FIRST launch mapping:
// qt = y<16 ? 31-y : y-16.  Co-resident 4-sets {y,y+8,y+16,y+24} still sum
// to a uniform 66 tiles, but the longest blocks (qt=31) launch first and
// the final wave of blocks is the SHORTEST (9-16 tiles) -> minimal drain
// tail. (v7's QBLK=128 regressed: doubled critical-path block length.)
__global__ __launch_bounds__(256, 3) void attn_kernel(
    const unsigned short* __restrict__ Qv, const unsigned short* __restrict__ Kv,
    const unsigned short* __restrict__ Vt, unsigned short* __restrict__ Aov) {
  __shared__ unsigned short Ks[3][4096];   // [buf][row 64][col 64] swizzled
  __shared__ unsigned short Vs[3][4096];   // [buf][d 64][kcol 64] swizzled
  const int bh = blockIdx.x;
  const int yy = blockIdx.y;
  const int qt = (yy < 16) ? (31 - yy) : (yy - 16);  // longest-first
  const int t = threadIdx.x;
  const int w = t >> 6, lane = t & 63, lq = lane & 15, quad = lane >> 4;
  const int l3 = lq & 7;

  const unsigned short* Qh = Qv + (size_t)bh * SV_ * D_;
  const unsigned short* Kh = Kv + (size_t)bh * SV_ * D_;
  const unsigned short* Vh = Vt + (size_t)bh * D_ * SV_;

  const int qrow = qt * 64 + w * 16 + lq;  // this lane's q row
  short8 bq0 = *(const short8*)(Qh + (size_t)qrow * 64 + quad * 8);
  short8 bq1 = *(const short8*)(Qh + (size_t)qrow * 64 + 32 + quad * 8);

  // Staging: lane-linear LDS granules; global side applies the XOR swizzle.
  const int sg = (lane & 7) ^ ((lane >> 3) & 7);  // granule ^ (row&7)
  const int r0 = w * 16 + (lane >> 3);            // row for issue 0 (+8 for issue 1)
  const unsigned short* Kg0 = Kh + r0 * 64 + sg * 8;
  const unsigned short* Vg0 = Vh + (size_t)r0 * SV_ + sg * 8;
  const int lds0 = w * 1024;       // shorts (16 rows x 64), wave-uniform
  const int lds1 = lds0 + 512;     // +8 rows

  auto stage = [&](int kt) {
    const int buf = kt % 3;
    const unsigned short* kg = Kg0 + kt * 4096;
    const unsigned short* vg = Vg0 + kt * 64;
    __builtin_amdgcn_global_load_lds(
        (const __attribute__((address_space(1))) unsigned int*)kg,
        (__attribute__((address_space(3))) unsigned int*)(&Ks[buf][lds0]), 16, 0, 0);
    __builtin_amdgcn_global_load_lds(
        (const __attribute__((address_space(1))) unsigned int*)(kg + 8 * 64),
        (__attribute__((address_space(3))) unsigned int*)(&Ks[buf][lds1]), 16, 0, 0);
    __builtin_amdgcn_global_load_lds(
        (const __attribute__((address_space(1))) unsigned int*)vg,
        (__attribute__((address_space(3))) unsigned int*)(&Vs[buf][lds0]), 16, 0, 0);
    __builtin_amdgcn_global_load_lds(
        (const __attribute__((address_space(1))) unsigned int*)(vg + (size_t)8 * SV_),
        (__attribute__((address_space(3))) unsigned int*)(&Vs[buf][lds1]), 16, 0, 0);
  };

  float l_sum = 0.f;
  f32x4 o_acc[4];
#pragma unroll
  for (int nd = 0; nd < 4; ++nd) o_acc[nd] = (f32x4){0.f, 0.f, 0.f, 0.f};

  const int nt = qt + 1;
  stage(0);
  if (nt > 1) stage(1);

  for (int kt = 0; kt < nt; ++kt) {
    const int buf = kt % 3;
    if (kt + 1 < nt) {
      asm volatile("s_waitcnt vmcnt(4)" ::: "memory");
    } else {
      asm volatile("s_waitcnt vmcnt(0)" ::: "memory");
    }
    asm volatile("s_barrier" ::: "memory");
    if (kt + 2 < nt) stage(kt + 2);   // overwrites buf (kt-1)%3: safe now

    // ---- K fragments from LDS ----
    const unsigned short* Kb = Ks[buf];
    short8 ka[4][2];
#pragma unroll
    for (int t4 = 0; t4 < 4; ++t4)
#pragma unroll
      for (int c = 0; c < 2; ++c)
        ka[t4][c] = *(const short8*)(Kb + (t4 * 16 + lq) * 64 + (((c * 4 + quad) ^ l3) * 8));

    // ---- S^T = K·Q^T (Q pre-scaled by SCALE*log2e) ----
    f32x4 s[4];
#pragma unroll
    for (int t4 = 0; t4 < 4; ++t4) {
      f32x4 z = (f32x4){0.f, 0.f, 0.f, 0.f};
      z = __builtin_amdgcn_mfma_f32_16x16x32_bf16(ka[t4][0], bq0, z, 0, 0, 0);
      s[t4] = __builtin_amdgcn_mfma_f32_16x16x32_bf16(ka[t4][1], bq1, z, 0, 0, 0);
    }

    // ---- p = exp2(s), diagonal mask, in-lane row-sum, in-register PV ----
    const bool diag = (kt == qt);
    const int kc0 = kt * 64 + quad * 4;
    const unsigned short* Vb = Vs[buf];
    float rs = 0.f;
    __builtin_amdgcn_s_setprio(1);
#pragma unroll
    for (int t4 = 0; t4 < 4; ++t4) {
      float p0 = EXP2(s[t4][0]), p1 = EXP2(s[t4][1]);
      float p2 = EXP2(s[t4][2]), p3 = EXP2(s[t4][3]);
      if (diag) {
        const int kc = kc0 + t4 * 16;
        if (kc + 0 > qrow) p0 = 0.f;
        if (kc + 1 > qrow) p1 = 0.f;
        if (kc + 2 > qrow) p2 = 0.f;
        if (kc + 3 > qrow) p3 = 0.f;
      }
      rs += (p0 + p1) + (p2 + p3);
      unsigned ww[2];
      ww[0] = pack_bf2(p0, p1);
      ww[1] = pack_bf2(p2, p3);
      short4b pb;
      __builtin_memcpy(&pb, ww, 8);
      const int cg = t4 * 2 + (quad >> 1);
      const int vcol = ((cg ^ l3) * 8) + (quad & 1) * 4;
#pragma unroll
      for (int nd = 0; nd < 4; ++nd) {
        short4b va4;
        __builtin_memcpy(&va4, Vb + (nd * 16 + lq) * 64 + vcol, 8);
        o_acc[nd] = __builtin_amdgcn_mfma_f32_16x16x16bf16_1k(va4, pb,
                                                              o_acc[nd], 0, 0, 0);
      }
    }
    __builtin_amdgcn_s_setprio(0);
    l_sum += rs;
  }

  // final cross-quad row-sum reduction
  l_sum += __shfl_xor(l_sum, 16);
  l_sum += __shfl_xor(l_sum, 32);

  const int b = bh >> 4, h = bh & 15;
  const float inv = 1.0f / l_sum;
  const int n = qrow >> 1, p = qrow & 1;
  unsigned short* dst = Aov + ((size_t)(b * 1024 + n)) * 2048 + (h * 2 + p) * 64;
#pragma unroll
  for (int nd = 0; nd < 4; ++nd) {
    uint2 dw;
    dw.x = pack_bf2(o_acc[nd][0] * inv, o_acc[nd][1] * inv);
    dw.y = pack_bf2(o_acc[nd][2] * inv, o_acc[nd][3] * inv);
    *(uint2*)(dst + nd * 16 + quad * 4) = dw;
  }
}

// ---------------------------------------------------------------------------
extern "C" void kernel_launch(void* const* d_in, const int* in_sizes, int n_in,
                              void* d_out, int out_size, void* d_ws, size_t ws_size,
                              hipStream_t stream) {
  (void)in_sizes; (void)n_in; (void)out_size; (void)ws_size;
  const float* x    = (const float*)d_in[0];
  const float* Wq   = (const float*)d_in[1];
  const float* Wk   = (const float*)d_in[2];
  const float* Wv   = (const float*)d_in[3];
  const float* Wo   = (const float*)d_in[4];
  const float* aq   = (const float*)d_in[5];
  const float* ak   = (const float*)d_in[6];
  const float* av   = (const float*)d_in[7];
  const float* coll = (const float*)d_in[8];
  float* out = (float*)d_out;

  char* ws = (char*)d_ws;
  const size_t MB = 1024 * 1024;
  unsigned short* Xb    = (unsigned short*)(ws);            // 4 MB  [0,4)
  unsigned short* Woeff = (unsigned short*)(ws + 4 * MB);   // 4 MB  [4,8)
  unsigned short* Weff  = (unsigned short*)(ws + 8 * MB);   // 12 MB [8,20)
  unsigned short* Qv    = (unsigned short*)(ws + 20 * MB);  // 8 MB  [20,28)
  unsigned short* Kv    = (unsigned short*)(ws + 28 * MB);  // 8 MB  [28,36)
  unsigned short* Vt    = (unsigned short*)(ws + 36 * MB);  // 8 MB  [36,44)
  // Weff dead after QKV GEMM; reuse:
  unsigned short* Aov   = (unsigned short*)(ws + 8 * MB);   // 8 MB  [8,16)

  prep_kernel<<<dim3(2240), dim3(256), 0, stream>>>(
      x, Wq, Wk, Wv, Wo, aq, ak, av, coll, Xb, Weff, Woeff);
  qkv_gemm128<<<dim3(16, 16, 3), dim3(256), 0, stream>>>(Xb, Weff, Qv, Kv, Vt);
  attn_kernel<<<dim3(32, 32), dim3(256), 0, stream>>>(Qv, Kv, Vt, Aov);
  gemm64p<<<dim3(32, 16), dim3(256), 0, stream>>>(Aov, Woeff, out);
}

// Round 14
// 183.233 us; speedup vs baseline: 1.0850x; 1.0197x over previous
//
#include <hip/hip_runtime.h>
#include <hip/hip_bf16.h>

// Problem constants
#define B_    2
#define S_    1024
#define HID_  1024
#define H_    16
#define P_    2
#define D_    64
#define SV_   2048   // S_*P_
#define NBH_  32     // B_*H_
// SCALE * log2(e) = 0.125 * 1.4426950408889634
#define SCALE_LOG2E 0.18033688f

typedef __attribute__((ext_vector_type(8))) short short8;
typedef __attribute__((ext_vector_type(4))) short short4b;
typedef __attribute__((ext_vector_type(4))) float f32x4;

#if __has_builtin(__builtin_amdgcn_exp2f)
#define EXP2(x) __builtin_amdgcn_exp2f(x)
#else
#define EXP2(x) exp2f(x)
#endif

__device__ __forceinline__ unsigned short f2bf(float f) {
  union { float f; unsigned u; } v; v.f = f;
  unsigned r = v.u + 0x7fffu + ((v.u >> 16) & 1u);
  return (unsigned short)(r >> 16);
}
__device__ __forceinline__ unsigned pack_bf2(float a, float b) {
  __hip_bfloat162 h = __float22bfloat162_rn(make_float2(a, b));
  unsigned u; __builtin_memcpy(&u, &h, 4);
  return u;
}

// ---------------------------------------------------------------------------
// Fused prep kernel (unchanged).
__global__ __launch_bounds__(256) void prep_kernel(
    const float* __restrict__ x,
    const float* __restrict__ Wq, const float* __restrict__ Wk,
    const float* __restrict__ Wv, const float* __restrict__ Wo,
    const float* __restrict__ aq, const float* __restrict__ ak,
    const float* __restrict__ av, const float* __restrict__ coll,
    unsigned short* __restrict__ Xb, unsigned short* __restrict__ Weff,
    unsigned short* __restrict__ Woeff) {
  __shared__ float shbuf[1536];
  const int bid = blockIdx.x;
  const int tid = threadIdx.x;

  if (bid < 1024) {
    const int n4 = (B_ * S_ * HID_) / 4;
    int i = bid * 256 + tid;
    const int stride = 1024 * 256;
    for (; i < n4; i += stride) {
      float4 v = ((const float4*)x)[i];
      ushort4 o;
      o.x = f2bf(v.x); o.y = f2bf(v.y); o.z = f2bf(v.z); o.w = f2bf(v.w);
      ((ushort4*)Xb)[i] = o;
    }
  } else if (bid < 1216) {
    const int wb = bid - 1024;
    const int d = wb & 63;
    const int t = wb >> 6;
    const float* W = (t == 0) ? Wq : ((t == 1) ? Wk : Wv);
    const float* A = (t == 0) ? aq : ((t == 1) ? ak : av);
    float (*Al)[32] = (float (*)[32])shbuf;
    for (int idx = tid; idx < 512; idx += 256) Al[idx >> 5][idx & 31] = A[idx];
    __syncthreads();
    const int e = tid * 4;
    float wr[16][4];
#pragma unroll
    for (int m = 0; m < 16; ++m) {
      float4 v = *(const float4*)(W + (size_t)(m * 64 + d) * 1024 + e);
      wr[m][0] = v.x; wr[m][1] = v.y; wr[m][2] = v.z; wr[m][3] = v.w;
    }
    for (int hp = 0; hp < 32; ++hp) {
      float acc0 = 0.f, acc1 = 0.f, acc2 = 0.f, acc3 = 0.f;
#pragma unroll
      for (int m = 0; m < 16; ++m) {
        float al = Al[m][hp];
        acc0 += al * wr[m][0]; acc1 += al * wr[m][1];
        acc2 += al * wr[m][2]; acc3 += al * wr[m][3];
      }
      int r = (hp >> 1) * 128 + (hp & 1) * 64 + d;
      ushort4 ov;
      ov.x = f2bf(acc0); ov.y = f2bf(acc1); ov.z = f2bf(acc2); ov.w = f2bf(acc3);
      *(ushort4*)(Weff + ((size_t)t * 2048 + r) * 1024 + e) = ov;
    }
  } else {
    const int f = bid - 1216;
    float* wrow = shbuf;
    float* cl = shbuf + 1024;
    for (int idx = tid; idx < 512; idx += 256) cl[idx] = coll[idx];
    for (int idx = tid; idx < 1024; idx += 256) wrow[idx] = Wo[(size_t)f * 1024 + idx];
    __syncthreads();
    for (int idx = tid; idx < 2048; idx += 256) {
      int o = idx >> 6, d = idx & 63;
      float acc = 0.f;
#pragma unroll
      for (int h = 0; h < 16; ++h) acc += wrow[h * 64 + d] * cl[h * 32 + o];
      Woeff[(size_t)f * 2048 + idx] = f2bf(acc);
    }
  }
}

// ---------------------------------------------------------------------------
// Unified QKV GEMM v3: same 128x128/BK=32/triple-buffer/one-barrier body as
// v2, but 1D grid (768) with a bijective XCD-AWARE REMAP:
//   xcd=n&7, j=n>>3; x=(j&7)|((xcd&1)<<3); rest=j>>3;
//   y=(rest&3)+(xcd>>1)*4; z=rest>>2.
// Default HIP linearization puts x in the low bits, so each XCD's 96
// co-resident blocks spanned ALL 16 y x 3 z -> ~12 MB of B-panels per
// 4 MB XCD-L2 (B reads missed L2, hammered L3). Remap gives each XCD
// 8x x 4y x 3z -> ~7 MB working set, most B re-reads become L2 hits.
__global__ __launch_bounds__(256, 3) void qkv_gemm128(
    const unsigned short* __restrict__ Xb,
    const unsigned short* __restrict__ Weff,
    unsigned short* __restrict__ Qd, unsigned short* __restrict__ Kd,
    unsigned short* __restrict__ Vd) {
  __shared__ unsigned short As[3][128 * 32];   // 24 KB
  __shared__ unsigned short Bs[3][128 * 32];   // 24 KB
  constexpr int K = 1024, NT = 32;              // K / 32
  const int t = threadIdx.x;
  const int wave = t >> 6, lane = t & 63, lq = lane & 15, quad = lane >> 4;
  const int wm = wave >> 1, wn = wave & 1;      // 2x2 waves, 64x64 each

  // ---- XCD-aware tile remap (bijective: 8 xcd x 96 j <-> 16x x 16y x 3z) --
  const int n = blockIdx.x;
  const int xcd = n & 7, j = n >> 3;
  const int bx = (j & 7) | ((xcd & 1) << 3);
  const int rest = j >> 3;                      // 0..11
  const int by = (rest & 3) + ((xcd >> 1) << 2);
  const int z = rest >> 2;                      // 0..2

  const int row0 = bx * 128, col0 = by * 128;
  const unsigned short* Ap = (z == 2) ? (Weff + (size_t)2 * 2048 * 1024) : Xb;
  const unsigned short* Bp = (z == 2) ? Xb : (Weff + (size_t)z * 2048 * 1024);

  const int srow = lane >> 2;                       // 0..15
  const int sgr = (lane & 3) ^ ((lane >> 3) & 3);   // pre-swizzled granule

  auto stage = [&](int kt, int buf) {
#pragma unroll
    for (int jj = 0; jj < 2; ++jj) {
      const int rloc = wave * 32 + jj * 16;  // wave-uniform chunk base row
      const unsigned short* ga =
          Ap + (size_t)(row0 + rloc + srow) * K + kt * 32 + sgr * 8;
      __builtin_amdgcn_global_load_lds(
          (const __attribute__((address_space(1))) unsigned int*)ga,
          (__attribute__((address_space(3))) unsigned int*)(&As[buf][rloc * 32]),
          16, 0, 0);
      const unsigned short* gb =
          Bp + (size_t)(col0 + rloc + srow) * K + kt * 32 + sgr * 8;
      __builtin_amdgcn_global_load_lds(
          (const __attribute__((address_space(1))) unsigned int*)gb,
          (__attribute__((address_space(3))) unsigned int*)(&Bs[buf][rloc * 32]),
          16, 0, 0);
    }
  };

  f32x4 acc[4][4];
#pragma unroll
  for (int mi = 0; mi < 4; ++mi)
#pragma unroll
    for (int ni = 0; ni < 4; ++ni) acc[mi][ni] = (f32x4){0.f, 0.f, 0.f, 0.f};

  stage(0, 0);
  stage(1, 1);

  const int swz4 = (lq >> 1) & 3;   // read-side granule XOR

  for (int kt = 0; kt < NT; ++kt) {
    const int buf = kt % 3;
    if (kt + 1 < NT) {
      asm volatile("s_waitcnt vmcnt(4)" ::: "memory");
    } else {
      asm volatile("s_waitcnt vmcnt(0)" ::: "memory");
    }
    asm volatile("s_barrier" ::: "memory");
    if (kt + 2 < NT) stage(kt + 2, (kt + 2) % 3);  // overwrites (kt-1)%3

    const unsigned short* __restrict__ Ab = &As[buf][0];
    const unsigned short* __restrict__ Bb = &Bs[buf][0];
    short8 af[4], bf[4];
#pragma unroll
    for (int mi = 0; mi < 4; ++mi)
      af[mi] = *(const short8*)(
          Ab + (wm * 64 + mi * 16 + lq) * 32 + ((quad ^ swz4) * 8));
#pragma unroll
    for (int ni = 0; ni < 4; ++ni)
      bf[ni] = *(const short8*)(
          Bb + (wn * 64 + ni * 16 + lq) * 32 + ((quad ^ swz4) * 8));
    __builtin_amdgcn_s_setprio(1);
#pragma unroll
    for (int mi = 0; mi < 4; ++mi)
#pragma unroll
      for (int ni = 0; ni < 4; ++ni)
        acc[mi][ni] = __builtin_amdgcn_mfma_f32_16x16x32_bf16(
            af[mi], bf[ni], acc[mi][ni], 0, 0, 0);
    __builtin_amdgcn_s_setprio(0);
  }

  // Epilogue: scattered bf16 stores into head-interleaved layouts.
#pragma unroll
  for (int mi = 0; mi < 4; ++mi) {
#pragma unroll
    for (int ni = 0; ni < 4; ++ni) {
#pragma unroll
      for (int i = 0; i < 4; ++i) {
        int grow = row0 + wm * 64 + mi * 16 + quad * 4 + i;
        int gcol = col0 + wn * 64 + ni * 16 + lq;
        float val = acc[mi][ni][i];
        if (z != 2) {
          if (z == 0) val *= SCALE_LOG2E;  // pre-scale Q for exp2-direct attn
          int b = grow >> 10, nn = grow & 1023;
          int h = gcol >> 7, p = (gcol >> 6) & 1, d = gcol & 63;
          unsigned short* dst = (z == 0) ? Qd : Kd;
          dst[((size_t)((b * 16 + h) * 2048) + nn * 2 + p) * 64 + d] = f2bf(val);
        } else {
          // grow = (h,p,d), gcol = (b, n)
          int h = grow >> 7, p = (grow >> 6) & 1, d = grow & 63;
          int b = gcol >> 10, nn = gcol & 1023;
          Vd[((size_t)((b * 16 + h) * 64 + d)) * 2048 + nn * 2 + p] = f2bf(val);
        }
      }
    }
  }
}

// ---------------------------------------------------------------------------
// Output GEMM v2: same 64x64/BK=64/triple-buffer body, 1D grid (512) with
// XCD-aware remap: x=(xcd&3)*8+(j&7), y=(xcd>>2)*8+(j>>3) -> each XCD gets
// 8x x 8y = 2 MB A + 2 MB B = fits its 4 MB L2.
__global__ __launch_bounds__(256) void gemm64p(
    const unsigned short* __restrict__ A,      // [2048 x 2048] row-major
    const unsigned short* __restrict__ Bbase,  // [1024 x 2048] (B^T form)
    float* __restrict__ Cf) {                  // [2048 x 1024]
  __shared__ unsigned short As[3][64 * 64];    // 24 KB
  __shared__ unsigned short Bs[3][64 * 64];    // 24 KB
  constexpr int K = 2048, N = 1024, NT = 32;   // K / 64
  const int t = threadIdx.x;
  const int wave = t >> 6, lane = t & 63, lrow = lane & 15, quad = lane >> 4;
  const int wm = wave >> 1, wn = wave & 1;     // 2x2 wave grid, 32x32 each

  // ---- XCD-aware tile remap (bijective: 8 xcd x 64 j <-> 32x x 16y) ----
  const int n = blockIdx.x;
  const int xcd = n & 7, j = n >> 3;
  const int bx = (xcd & 3) * 8 + (j & 7);      // 0..31
  const int by = (xcd >> 2) * 8 + (j >> 3);    // 0..15

  const int row0 = bx * 64, col0 = by * 64;
  const int srow8 = lane >> 3;
  const int sslot = (lane & 7) ^ srow8;        // pre-swizzled global slot
  const int swz = lrow & 7;

  auto stage = [&](int kt, int buf) {
#pragma unroll
    for (int jj = 0; jj < 2; ++jj) {
      const int rloc = wave * 16 + jj * 8;
      const unsigned short* ga =
          A + (size_t)(row0 + rloc + srow8) * K + kt * 64 + sslot * 8;
      __builtin_amdgcn_global_load_lds(
          (const __attribute__((address_space(1))) unsigned int*)ga,
          (__attribute__((address_space(3))) unsigned int*)(&As[buf][rloc * 64]),
          16, 0, 0);
      const unsigned short* gb =
          Bbase + (size_t)(col0 + rloc + srow8) * K + kt * 64 + sslot * 8;
      __builtin_amdgcn_global_load_lds(
          (const __attribute__((address_space(1))) unsigned int*)gb,
          (__attribute__((address_space(3))) unsigned int*)(&Bs[buf][rloc * 64]),
          16, 0, 0);
    }
  };

  f32x4 acc[2][2];
#pragma unroll
  for (int mi = 0; mi < 2; ++mi)
#pragma unroll
    for (int ni = 0; ni < 2; ++ni) acc[mi][ni] = (f32x4){0.f, 0.f, 0.f, 0.f};

  stage(0, 0);
  stage(1, 1);

  for (int kt = 0; kt < NT; ++kt) {
    const int buf = kt % 3;
    if (kt < NT - 1) {
      asm volatile("s_waitcnt vmcnt(4)" ::: "memory");  // tile kt landed
    } else {
      asm volatile("s_waitcnt vmcnt(0)" ::: "memory");
    }
    asm volatile("s_barrier" ::: "memory");
    if (kt + 2 < NT) stage(kt + 2, (kt + 2) % 3);

    const unsigned short* __restrict__ Ab = &As[buf][0];
    const unsigned short* __restrict__ Bb = &Bs[buf][0];
    short8 af[2][2], bf[2][2];
#pragma unroll
    for (int mi = 0; mi < 2; ++mi)
#pragma unroll
      for (int ks = 0; ks < 2; ++ks)
        af[mi][ks] = *(const short8*)(
            Ab + (wm * 32 + mi * 16 + lrow) * 64 + (((ks * 4 + quad) ^ swz) * 8));
#pragma unroll
    for (int ni = 0; ni < 2; ++ni)
#pragma unroll
      for (int ks = 0; ks < 2; ++ks)
        bf[ni][ks] = *(const short8*)(
            Bb + (wn * 32 + ni * 16 + lrow) * 64 + (((ks * 4 + quad) ^ swz) * 8));
    __builtin_amdgcn_s_setprio(1);
#pragma unroll
    for (int mi = 0; mi < 2; ++mi)
#pragma unroll
      for (int ni = 0; ni < 2; ++ni) {
        acc[mi][ni] = __builtin_amdgcn_mfma_f32_16x16x32_bf16(
            af[mi][0], bf[ni][0], acc[mi][ni], 0, 0, 0);
        acc[mi][ni] = __builtin_amdgcn_mfma_f32_16x16x32_bf16(
            af[mi][1], bf[ni][1], acc[mi][ni], 0, 0, 0);
      }
    __builtin_amdgcn_s_setprio(0);
  }

#pragma unroll
  for (int mi = 0; mi < 2; ++mi)
#pragma unroll
    for (int ni = 0; ni < 2; ++ni)
#pragma unroll
      for (int i = 0; i < 4; ++i) {
        int grow = row0 + wm * 32 + mi * 16 + quad * 4 + i;
        int gcol = col0 + wn * 32 + ni * 16 + lrow;
        Cf[(size_t)grow * N + gcol] = acc[mi][ni][i];
      }
}

// ---------------------------------------------------------------------------
// Causal flash attention v6b (unchanged from round 13): triple-buffered
// K/V, one barrier + one counted vmcnt per tile, in-register P, Q
// pre-scaled, longest-first launch mapping.
__global__ __launch_bounds__(256, 3) void attn_kernel(
    const unsigned short* __restrict__ Qv, const unsigned short* __restrict__ Kv,
    const unsigned short* __restrict__ Vt, unsigned short* __restrict__ Aov) {
  __shared__ unsigned short Ks[3][4096];   // [buf][row 64][col 64] swizzled
  __shared__ unsigned short Vs[3][4096];   // [buf][d 64][kcol 64] swizzled
  const int bh = blockIdx.x;
  const int yy = blockIdx.y;
  const int qt = (yy < 16) ? (31 - yy) : (yy - 16);  // longest-first
  const int t = threadIdx.x;
  const int w = t >> 6, lane = t & 63, lq = lane & 15, quad = lane >> 4;
  const int l3 = lq & 7;

  const unsigned short* Qh = Qv + (size_t)bh * SV_ * D_;
  const unsigned short* Kh = Kv + (size_t)bh * SV_ * D_;
  const unsigned short* Vh = Vt + (size_t)bh * D_ * SV_;

  const int qrow = qt * 64 + w * 16 + lq;  // this lane's q row
  short8 bq0 = *(const short8*)(Qh + (size_t)qrow * 64 + quad * 8);
  short8 bq1 = *(const short8*)(Qh + (size_t)qrow * 64 + 32 + quad * 8);

  // Staging: lane-linear LDS granules; global side applies the XOR swizzle.
  const int sg = (lane & 7) ^ ((lane >> 3) & 7);  // granule ^ (row&7)
  const int r0 = w * 16 + (lane >> 3);            // row for issue 0 (+8 for issue 1)
  const unsigned short* Kg0 = Kh + r0 * 64 + sg * 8;
  const unsigned short* Vg0 = Vh + (size_t)r0 * SV_ + sg * 8;
  const int lds0 = w * 1024;       // shorts (16 rows x 64), wave-uniform
  const int lds1 = lds0 + 512;     // +8 rows

  auto stage = [&](int kt) {
    const int buf = kt % 3;
    const unsigned short* kg = Kg0 + kt * 4096;
    const unsigned short* vg = Vg0 + kt * 64;
    __builtin_amdgcn_global_load_lds(
        (const __attribute__((address_space(1))) unsigned int*)kg,
        (__attribute__((address_space(3))) unsigned int*)(&Ks[buf][lds0]), 16, 0, 0);
    __builtin_amdgcn_global_load_lds(
        (const __attribute__((address_space(1))) unsigned int*)(kg + 8 * 64),
        (__attribute__((address_space(3))) unsigned int*)(&Ks[buf][lds1]), 16, 0, 0);
    __builtin_amdgcn_global_load_lds(
        (const __attribute__((address_space(1))) unsigned int*)vg,
        (__attribute__((address_space(3))) unsigned int*)(&Vs[buf][lds0]), 16, 0, 0);
    __builtin_amdgcn_global_load_lds(
        (const __attribute__((address_space(1))) unsigned int*)(vg + (size_t)8 * SV_),
        (__attribute__((address_space(3))) unsigned int*)(&Vs[buf][lds1]), 16, 0, 0);
  };

  float l_sum = 0.f;
  f32x4 o_acc[4];
#pragma unroll
  for (int nd = 0; nd < 4; ++nd) o_acc[nd] = (f32x4){0.f, 0.f, 0.f, 0.f};

  const int nt = qt + 1;
  stage(0);
  if (nt > 1) stage(1);

  for (int kt = 0; kt < nt; ++kt) {
    const int buf = kt % 3;
    if (kt + 1 < nt) {
      asm volatile("s_waitcnt vmcnt(4)" ::: "memory");
    } else {
      asm volatile("s_waitcnt vmcnt(0)" ::: "memory");
    }
    asm volatile("s_barrier" ::: "memory");
    if (kt + 2 < nt) stage(kt + 2);   // overwrites buf (kt-1)%3: safe now

    // ---- K fragments from LDS ----
    const unsigned short* Kb = Ks[buf];
    short8 ka[4][2];
#pragma unroll
    for (int t4 = 0; t4 < 4; ++t4)
#pragma unroll
      for (int c = 0; c < 2; ++c)
        ka[t4][c] = *(const short8*)(Kb + (t4 * 16 + lq) * 64 + (((c * 4 + quad) ^ l3) * 8));

    // ---- S^T = K·Q^T (Q pre-scaled by SCALE*log2e) ----
    f32x4 s[4];
#pragma unroll
    for (int t4 = 0; t4 < 4; ++t4) {
      f32x4 z = (f32x4){0.f, 0.f, 0.f, 0.f};
      z = __builtin_amdgcn_mfma_f32_16x16x32_bf16(ka[t4][0], bq0, z, 0, 0, 0);
      s[t4] = __builtin_amdgcn_mfma_f32_16x16x32_bf16(ka[t4][1], bq1, z, 0, 0, 0);
    }

    // ---- p = exp2(s), diagonal mask, in-lane row-sum, in-register PV ----
    const bool diag = (kt == qt);
    const int kc0 = kt * 64 + quad * 4;
    const unsigned short* Vb = Vs[buf];
    float rs = 0.f;
    __builtin_amdgcn_s_setprio(1);
#pragma unroll
    for (int t4 = 0; t4 < 4; ++t4) {
      float p0 = EXP2(s[t4][0]), p1 = EXP2(s[t4][1]);
      float p2 = EXP2(s[t4][2]), p3 = EXP2(s[t4][3]);
      if (diag) {
        const int kc = kc0 + t4 * 16;
        if (kc + 0 > qrow) p0 = 0.f;
        if (kc + 1 > qrow) p1 = 0.f;
        if (kc + 2 > qrow) p2 = 0.f;
        if (kc + 3 > qrow) p3 = 0.f;
      }
      rs += (p0 + p1) + (p2 + p3);
      unsigned ww[2];
      ww[0] = pack_bf2(p0, p1);
      ww[1] = pack_bf2(p2, p3);
      short4b pb;
      __builtin_memcpy(&pb, ww, 8);
      const int cg = t4 * 2 + (quad >> 1);
      const int vcol = ((cg ^ l3) * 8) + (quad & 1) * 4;
#pragma unroll
      for (int nd = 0; nd < 4; ++nd) {
        short4b va4;
        __builtin_memcpy(&va4, Vb + (nd * 16 + lq) * 64 + vcol, 8);
        o_acc[nd] = __builtin_amdgcn_mfma_f32_16x16x16bf16_1k(va4, pb,
                                                              o_acc[nd], 0, 0, 0);
      }
    }
    __builtin_amdgcn_s_setprio(0);
    l_sum += rs;
  }

  // final cross-quad row-sum reduction
  l_sum += __shfl_xor(l_sum, 16);
  l_sum += __shfl_xor(l_sum, 32);

  const int b = bh >> 4, h = bh & 15;
  const float inv = 1.0f / l_sum;
  const int n = qrow >> 1, p = qrow & 1;
  unsigned short* dst = Aov + ((size_t)(b * 1024 + n)) * 2048 + (h * 2 + p) * 64;
#pragma unroll
  for (int nd = 0; nd < 4; ++nd) {
    uint2 dw;
    dw.x = pack_bf2(o_acc[nd][0] * inv, o_acc[nd][1] * inv);
    dw.y = pack_bf2(o_acc[nd][2] * inv, o_acc[nd][3] * inv);
    *(uint2*)(dst + nd * 16 + quad * 4) = dw;
  }
}

// ---------------------------------------------------------------------------
extern "C" void kernel_launch(void* const* d_in, const int* in_sizes, int n_in,
                              void* d_out, int out_size, void* d_ws, size_t ws_size,
                              hipStream_t stream) {
  (void)in_sizes; (void)n_in; (void)out_size; (void)ws_size;
  const float* x    = (const float*)d_in[0];
  const float* Wq   = (const float*)d_in[1];
  const float* Wk   = (const float*)d_in[2];
  const float* Wv   = (const float*)d_in[3];
  const float* Wo   = (const float*)d_in[4];
  const float* aq   = (const float*)d_in[5];
  const float* ak   = (const float*)d_in[6];
  const float* av   = (const float*)d_in[7];
  const float* coll = (const float*)d_in[8];
  float* out = (float*)d_out;

  char* ws = (char*)d_ws;
  const size_t MB = 1024 * 1024;
  unsigned short* Xb    = (unsigned short*)(ws);            // 4 MB  [0,4)
  unsigned short* Woeff = (unsigned short*)(ws + 4 * MB);   // 4 MB  [4,8)
  unsigned short* Weff  = (unsigned short*)(ws + 8 * MB);   // 12 MB [8,20)
  unsigned short* Qv    = (unsigned short*)(ws + 20 * MB);  // 8 MB  [20,28)
  unsigned short* Kv    = (unsigned short*)(ws + 28 * MB);  // 8 MB  [28,36)
  unsigned short* Vt    = (unsigned short*)(ws + 36 * MB);  // 8 MB  [36,44)
  // Weff dead after QKV GEMM; reuse:
  unsigned short* Aov   = (unsigned short*)(ws + 8 * MB);   // 8 MB  [8,16)

  prep_kernel<<<dim3(2240), dim3(256), 0, stream>>>(
      x, Wq, Wk, Wv, Wo, aq, ak, av, coll, Xb, Weff, Woeff);
  qkv_gemm128<<<dim3(768), dim3(256), 0, stream>>>(Xb, Weff, Qv, Kv, Vt);
  attn_kernel<<<dim3(32, 32), dim3(256), 0, stream>>>(Qv, Kv, Vt, Aov);
  gemm64p<<<dim3(512), dim3(256), 0, stream>>>(Aov, Woeff, out);
}

// Round 16
// 181.904 us; speedup vs baseline: 1.0929x; 1.0073x over previous
//
#include <hip/hip_runtime.h>
#include <hip/hip_bf16.h>

// Problem constants
#define B_    2
#define S_    1024
#define HID_  1024
#define H_    16
#define P_    2
#define D_    64
#define SV_   2048   // S_*P_
#define NBH_  32     // B_*H_
// SCALE * log2(e) = 0.125 * 1.4426950408889634
#define SCALE_LOG2E 0.18033688f

typedef __attribute__((ext_vector_type(8))) short short8;
typedef __attribute__((ext_vector_type(4))) short short4b;
typedef __attribute__((ext_vector_type(4))) float f32x4;

#if __has_builtin(__builtin_amdgcn_exp2f)
#define EXP2(x) __builtin_amdgcn_exp2f(x)
#else
#define EXP2(x) exp2f(x)
#endif

__device__ __forceinline__ unsigned short f2bf(float f) {
  union { float f; unsigned u; } v; v.f = f;
  unsigned r = v.u + 0x7fffu + ((v.u >> 16) & 1u);
  return (unsigned short)(r >> 16);
}
__device__ __forceinline__ unsigned pack_bf2(float a, float b) {
  __hip_bfloat162 h = __float22bfloat162_rn(make_float2(a, b));
  unsigned u; __builtin_memcpy(&u, &h, 4);
  return u;
}

// ---------------------------------------------------------------------------
// Fused prep kernel (unchanged).
__global__ __launch_bounds__(256) void prep_kernel(
    const float* __restrict__ x,
    const float* __restrict__ Wq, const float* __restrict__ Wk,
    const float* __restrict__ Wv, const float* __restrict__ Wo,
    const float* __restrict__ aq, const float* __restrict__ ak,
    const float* __restrict__ av, const float* __restrict__ coll,
    unsigned short* __restrict__ Xb, unsigned short* __restrict__ Weff,
    unsigned short* __restrict__ Woeff) {
  __shared__ float shbuf[1536];
  const int bid = blockIdx.x;
  const int tid = threadIdx.x;

  if (bid < 1024) {
    const int n4 = (B_ * S_ * HID_) / 4;
    int i = bid * 256 + tid;
    const int stride = 1024 * 256;
    for (; i < n4; i += stride) {
      float4 v = ((const float4*)x)[i];
      ushort4 o;
      o.x = f2bf(v.x); o.y = f2bf(v.y); o.z = f2bf(v.z); o.w = f2bf(v.w);
      ((ushort4*)Xb)[i] = o;
    }
  } else if (bid < 1216) {
    const int wb = bid - 1024;
    const int d = wb & 63;
    const int t = wb >> 6;
    const float* W = (t == 0) ? Wq : ((t == 1) ? Wk : Wv);
    const float* A = (t == 0) ? aq : ((t == 1) ? ak : av);
    float (*Al)[32] = (float (*)[32])shbuf;
    for (int idx = tid; idx < 512; idx += 256) Al[idx >> 5][idx & 31] = A[idx];
    __syncthreads();
    const int e = tid * 4;
    float wr[16][4];
#pragma unroll
    for (int m = 0; m < 16; ++m) {
      float4 v = *(const float4*)(W + (size_t)(m * 64 + d) * 1024 + e);
      wr[m][0] = v.x; wr[m][1] = v.y; wr[m][2] = v.z; wr[m][3] = v.w;
    }
    for (int hp = 0; hp < 32; ++hp) {
      float acc0 = 0.f, acc1 = 0.f, acc2 = 0.f, acc3 = 0.f;
#pragma unroll
      for (int m = 0; m < 16; ++m) {
        float al = Al[m][hp];
        acc0 += al * wr[m][0]; acc1 += al * wr[m][1];
        acc2 += al * wr[m][2]; acc3 += al * wr[m][3];
      }
      int r = (hp >> 1) * 128 + (hp & 1) * 64 + d;
      ushort4 ov;
      ov.x = f2bf(acc0); ov.y = f2bf(acc1); ov.z = f2bf(acc2); ov.w = f2bf(acc3);
      *(ushort4*)(Weff + ((size_t)t * 2048 + r) * 1024 + e) = ov;
    }
  } else {
    const int f = bid - 1216;
    float* wrow = shbuf;
    float* cl = shbuf + 1024;
    for (int idx = tid; idx < 512; idx += 256) cl[idx] = coll[idx];
    for (int idx = tid; idx < 1024; idx += 256) wrow[idx] = Wo[(size_t)f * 1024 + idx];
    __syncthreads();
    for (int idx = tid; idx < 2048; idx += 256) {
      int o = idx >> 6, d = idx & 63;
      float acc = 0.f;
#pragma unroll
      for (int h = 0; h < 16; ++h) acc += wrow[h * 64 + d] * cl[h * 32 + o];
      Woeff[(size_t)f * 2048 + idx] = f2bf(acc);
    }
  }
}

// ---------------------------------------------------------------------------
// Unified QKV GEMM v3: same 128x128/BK=32/triple-buffer/one-barrier body as
// v2, but 1D grid (768) with a bijective XCD-AWARE REMAP:
//   xcd=n&7, j=n>>3; x=(j&7)|((xcd&1)<<3); rest=j>>3;
//   y=(rest&3)+(xcd>>1)*4; z=rest>>2.
// Remap gives each XCD 8x x 4y x 3z -> ~7 MB working set, most B re-reads
// become L2 hits (validated: -3.6 us in round 14).
__global__ __launch_bounds__(256, 3) void qkv_gemm128(
    const unsigned short* __restrict__ Xb,
    const unsigned short* __restrict__ Weff,
    unsigned short* __restrict__ Qd, unsigned short* __restrict__ Kd,
    unsigned short* __restrict__ Vd) {
  __shared__ unsigned short As[3][128 * 32];   // 24 KB
  __shared__ unsigned short Bs[3][128 * 32];   // 24 KB
  constexpr int K = 1024, NT = 32;              // K / 32
  const int t = threadIdx.x;
  const int wave = t >> 6, lane = t & 63, lq = lane & 15, quad = lane >> 4;
  const int wm = wave >> 1, wn = wave & 1;      // 2x2 waves, 64x64 each

  // ---- XCD-aware tile remap (bijective: 8 xcd x 96 j <-> 16x x 16y x 3z) --
  const int n = blockIdx.x;
  const int xcd = n & 7, j = n >> 3;
  const int bx = (j & 7) | ((xcd & 1) << 3);
  const int rest = j >> 3;                      // 0..11
  const int by = (rest & 3) + ((xcd >> 1) << 2);
  const int z = rest >> 2;                      // 0..2

  const int row0 = bx * 128, col0 = by * 128;
  const unsigned short* Ap = (z == 2) ? (Weff + (size_t)2 * 2048 * 1024) : Xb;
  const unsigned short* Bp = (z == 2) ? Xb : (Weff + (size_t)z * 2048 * 1024);

  const int srow = lane >> 2;                       // 0..15
  const int sgr = (lane & 3) ^ ((lane >> 3) & 3);   // pre-swizzled granule

  auto stage = [&](int kt, int buf) {
#pragma unroll
    for (int jj = 0; jj < 2; ++jj) {
      const int rloc = wave * 32 + jj * 16;  // wave-uniform chunk base row
      const unsigned short* ga =
          Ap + (size_t)(row0 + rloc + srow) * K + kt * 32 + sgr * 8;
      __builtin_amdgcn_global_load_lds(
          (const __attribute__((address_space(1))) unsigned int*)ga,
          (__attribute__((address_space(3))) unsigned int*)(&As[buf][rloc * 32]),
          16, 0, 0);
      const unsigned short* gb =
          Bp + (size_t)(col0 + rloc + srow) * K + kt * 32 + sgr * 8;
      __builtin_amdgcn_global_load_lds(
          (const __attribute__((address_space(1))) unsigned int*)gb,
          (__attribute__((address_space(3))) unsigned int*)(&Bs[buf][rloc * 32]),
          16, 0, 0);
    }
  };

  f32x4 acc[4][4];
#pragma unroll
  for (int mi = 0; mi < 4; ++mi)
#pragma unroll
    for (int ni = 0; ni < 4; ++ni) acc[mi][ni] = (f32x4){0.f, 0.f, 0.f, 0.f};

  stage(0, 0);
  stage(1, 1);

  const int swz4 = (lq >> 1) & 3;   // read-side granule XOR

  for (int kt = 0; kt < NT; ++kt) {
    const int buf = kt % 3;
    if (kt + 1 < NT) {
      asm volatile("s_waitcnt vmcnt(4)" ::: "memory");
    } else {
      asm volatile("s_waitcnt vmcnt(0)" ::: "memory");
    }
    asm volatile("s_barrier" ::: "memory");
    if (kt + 2 < NT) stage(kt + 2, (kt + 2) % 3);  // overwrites (kt-1)%3

    const unsigned short* __restrict__ Ab = &As[buf][0];
    const unsigned short* __restrict__ Bb = &Bs[buf][0];
    short8 af[4], bf[4];
#pragma unroll
    for (int mi = 0; mi < 4; ++mi)
      af[mi] = *(const short8*)(
          Ab + (wm * 64 + mi * 16 + lq) * 32 + ((quad ^ swz4) * 8));
#pragma unroll
    for (int ni = 0; ni < 4; ++ni)
      bf[ni] = *(const short8*)(
          Bb + (wn * 64 + ni * 16 + lq) * 32 + ((quad ^ swz4) * 8));
    __builtin_amdgcn_s_setprio(1);
#pragma unroll
    for (int mi = 0; mi < 4; ++mi)
#pragma unroll
      for (int ni = 0; ni < 4; ++ni)
        acc[mi][ni] = __builtin_amdgcn_mfma_f32_16x16x32_bf16(
            af[mi], bf[ni], acc[mi][ni], 0, 0, 0);
    __builtin_amdgcn_s_setprio(0);
  }

  // Epilogue: scattered bf16 stores into head-interleaved layouts.
#pragma unroll
  for (int mi = 0; mi < 4; ++mi) {
#pragma unroll
    for (int ni = 0; ni < 4; ++ni) {
#pragma unroll
      for (int i = 0; i < 4; ++i) {
        int grow = row0 + wm * 64 + mi * 16 + quad * 4 + i;
        int gcol = col0 + wn * 64 + ni * 16 + lq;
        float val = acc[mi][ni][i];
        if (z != 2) {
          if (z == 0) val *= SCALE_LOG2E;  // pre-scale Q for exp2-direct attn
          int b = grow >> 10, nn = grow & 1023;
          int h = gcol >> 7, p = (gcol >> 6) & 1, d = gcol & 63;
          unsigned short* dst = (z == 0) ? Qd : Kd;
          dst[((size_t)((b * 16 + h) * 2048) + nn * 2 + p) * 64 + d] = f2bf(val);
        } else {
          // grow = (h,p,d), gcol = (b, n)
          int h = grow >> 7, p = (grow >> 6) & 1, d = grow & 63;
          int b = gcol >> 10, nn = gcol & 1023;
          Vd[((size_t)((b * 16 + h) * 64 + d)) * 2048 + nn * 2 + p] = f2bf(val);
        }
      }
    }
  }
}

// ---------------------------------------------------------------------------
// Output GEMM v2: same 64x64/BK=64/triple-buffer body, 1D grid (512) with
// XCD-aware remap: x=(xcd&3)*8+(j&7), y=(xcd>>2)*8+(j>>3) -> each XCD gets
// 8x x 8y = 2 MB A + 2 MB B = fits its 4 MB L2.
__global__ __launch_bounds__(256) void gemm64p(
    const unsigned short* __restrict__ A,      // [2048 x 2048] row-major
    const unsigned short* __restrict__ Bbase,  // [1024 x 2048] (B^T form)
    float* __restrict__ Cf) {                  // [2048 x 1024]
  __shared__ unsigned short As[3][64 * 64];    // 24 KB
  __shared__ unsigned short Bs[3][64 * 64];    // 24 KB
  constexpr int K = 2048, N = 1024, NT = 32;   // K / 64
  const int t = threadIdx.x;
  const int wave = t >> 6, lane = t & 63, lrow = lane & 15, quad = lane >> 4;
  const int wm = wave >> 1, wn = wave & 1;     // 2x2 wave grid, 32x32 each

  // ---- XCD-aware tile remap (bijective: 8 xcd x 64 j <-> 32x x 16y) ----
  const int n = blockIdx.x;
  const int xcd = n & 7, j = n >> 3;
  const int bx = (xcd & 3) * 8 + (j & 7);      // 0..31
  const int by = (xcd >> 2) * 8 + (j >> 3);    // 0..15

  const int row0 = bx * 64, col0 = by * 64;
  const int srow8 = lane >> 3;
  const int sslot = (lane & 7) ^ srow8;        // pre-swizzled global slot
  const int swz = lrow & 7;

  auto stage = [&](int kt, int buf) {
#pragma unroll
    for (int jj = 0; jj < 2; ++jj) {
      const int rloc = wave * 16 + jj * 8;
      const unsigned short* ga =
          A + (size_t)(row0 + rloc + srow8) * K + kt * 64 + sslot * 8;
      __builtin_amdgcn_global_load_lds(
          (const __attribute__((address_space(1))) unsigned int*)ga,
          (__attribute__((address_space(3))) unsigned int*)(&As[buf][rloc * 64]),
          16, 0, 0);
      const unsigned short* gb =
          Bbase + (size_t)(col0 + rloc + srow8) * K + kt * 64 + sslot * 8;
      __builtin_amdgcn_global_load_lds(
          (const __attribute__((address_space(1))) unsigned int*)gb,
          (__attribute__((address_space(3))) unsigned int*)(&Bs[buf][rloc * 64]),
          16, 0, 0);
    }
  };

  f32x4 acc[2][2];
#pragma unroll
  for (int mi = 0; mi < 2; ++mi)
#pragma unroll
    for (int ni = 0; ni < 2; ++ni) acc[mi][ni] = (f32x4){0.f, 0.f, 0.f, 0.f};

  stage(0, 0);
  stage(1, 1);

  for (int kt = 0; kt < NT; ++kt) {
    const int buf = kt % 3;
    if (kt < NT - 1) {
      asm volatile("s_waitcnt vmcnt(4)" ::: "memory");  // tile kt landed
    } else {
      asm volatile("s_waitcnt vmcnt(0)" ::: "memory");
    }
    asm volatile("s_barrier" ::: "memory");
    if (kt + 2 < NT) stage(kt + 2, (kt + 2) % 3);

    const unsigned short* __restrict__ Ab = &As[buf][0];
    const unsigned short* __restrict__ Bb = &Bs[buf][0];
    short8 af[2][2], bf[2][2];
#pragma unroll
    for (int mi = 0; mi < 2; ++mi)
#pragma unroll
      for (int ks = 0; ks < 2; ++ks)
        af[mi][ks] = *(const short8*)(
            Ab + (wm * 32 + mi * 16 + lrow) * 64 + (((ks * 4 + quad) ^ swz) * 8));
#pragma unroll
    for (int ni = 0; ni < 2; ++ni)
#pragma unroll
      for (int ks = 0; ks < 2; ++ks)
        bf[ni][ks] = *(const short8*)(
            Bb + (wn * 32 + ni * 16 + lrow) * 64 + (((ks * 4 + quad) ^ swz) * 8));
    __builtin_amdgcn_s_setprio(1);
#pragma unroll
    for (int mi = 0; mi < 2; ++mi)
#pragma unroll
      for (int ni = 0; ni < 2; ++ni) {
        acc[mi][ni] = __builtin_amdgcn_mfma_f32_16x16x32_bf16(
            af[mi][0], bf[ni][0], acc[mi][ni], 0, 0, 0);
        acc[mi][ni] = __builtin_amdgcn_mfma_f32_16x16x32_bf16(
            af[mi][1], bf[ni][1], acc[mi][ni], 0, 0, 0);
      }
    __builtin_amdgcn_s_setprio(0);
  }

#pragma unroll
  for (int mi = 0; mi < 2; ++mi)
#pragma unroll
    for (int ni = 0; ni < 2; ++ni)
#pragma unroll
      for (int i = 0; i < 4; ++i) {
        int grow = row0 + wm * 32 + mi * 16 + quad * 4 + i;
        int gcol = col0 + wn * 32 + ni * 16 + lrow;
        Cf[(size_t)grow * N + gcol] = acc[mi][ni][i];
      }
}

// ---------------------------------------------------------------------------
// Causal flash attention v6b (reverted to the round-14 PASSING config):
// triple-buffered K/V, one barrier + one counted vmcnt per tile,
// in-register P, Q pre-scaled, longest-first launch mapping, 2D grid
// (32 bh, 32 y). The round-15 XCD-aware 1D remap produced nondeterministic
// post-timing divergence (timing-dependent race exposed by changed
// co-residency) and is abandoned.
__global__ __launch_bounds__(256, 3) void attn_kernel(
    const unsigned short* __restrict__ Qv, const unsigned short* __restrict__ Kv,
    const unsigned short* __restrict__ Vt, unsigned short* __restrict__ Aov) {
  __shared__ unsigned short Ks[3][4096];   // [buf][row 64][col 64] swizzled
  __shared__ unsigned short Vs[3][4096];   // [buf][d 64][kcol 64] swizzled
  const int bh = blockIdx.x;
  const int yy = blockIdx.y;
  const int qt = (yy < 16) ? (31 - yy) : (yy - 16);  // longest-first
  const int t = threadIdx.x;
  const int w = t >> 6, lane = t & 63, lq = lane & 15, quad = lane >> 4;
  const int l3 = lq & 7;

  const unsigned short* Qh = Qv + (size_t)bh * SV_ * D_;
  const unsigned short* Kh = Kv + (size_t)bh * SV_ * D_;
  const unsigned short* Vh = Vt + (size_t)bh * D_ * SV_;

  const int qrow = qt * 64 + w * 16 + lq;  // this lane's q row
  short8 bq0 = *(const short8*)(Qh + (size_t)qrow * 64 + quad * 8);
  short8 bq1 = *(const short8*)(Qh + (size_t)qrow * 64 + 32 + quad * 8);

  // Staging: lane-linear LDS granules; global side applies the XOR swizzle.
  const int sg = (lane & 7) ^ ((lane >> 3) & 7);  // granule ^ (row&7)
  const int r0 = w * 16 + (lane >> 3);            // row for issue 0 (+8 for issue 1)
  const unsigned short* Kg0 = Kh + r0 * 64 + sg * 8;
  const unsigned short* Vg0 = Vh + (size_t)r0 * SV_ + sg * 8;
  const int lds0 = w * 1024;       // shorts (16 rows x 64), wave-uniform
  const int lds1 = lds0 + 512;     // +8 rows

  auto stage = [&](int kt) {
    const int buf = kt % 3;
    const unsigned short* kg = Kg0 + kt * 4096;
    const unsigned short* vg = Vg0 + kt * 64;
    __builtin_amdgcn_global_load_lds(
        (const __attribute__((address_space(1))) unsigned int*)kg,
        (__attribute__((address_space(3))) unsigned int*)(&Ks[buf][lds0]), 16, 0, 0);
    __builtin_amdgcn_global_load_lds(
        (const __attribute__((address_space(1))) unsigned int*)(kg + 8 * 64),
        (__attribute__((address_space(3))) unsigned int*)(&Ks[buf][lds1]), 16, 0, 0);
    __builtin_amdgcn_global_load_lds(
        (const __attribute__((address_space(1))) unsigned int*)vg,
        (__attribute__((address_space(3))) unsigned int*)(&Vs[buf][lds0]), 16, 0, 0);
    __builtin_amdgcn_global_load_lds(
        (const __attribute__((address_space(1))) unsigned int*)(vg + (size_t)8 * SV_),
        (__attribute__((address_space(3))) unsigned int*)(&Vs[buf][lds1]), 16, 0, 0);
  };

  float l_sum = 0.f;
  f32x4 o_acc[4];
#pragma unroll
  for (int nd = 0; nd < 4; ++nd) o_acc[nd] = (f32x4){0.f, 0.f, 0.f, 0.f};

  const int nt = qt + 1;
  stage(0);
  if (nt > 1) stage(1);

  for (int kt = 0; kt < nt; ++kt) {
    const int buf = kt % 3;
    if (kt + 1 < nt) {
      asm volatile("s_waitcnt vmcnt(4)" ::: "memory");
    } else {
      asm volatile("s_waitcnt vmcnt(0)" ::: "memory");
    }
    asm volatile("s_barrier" ::: "memory");
    if (kt + 2 < nt) stage(kt + 2);   // overwrites buf (kt-1)%3: safe now

    // ---- K fragments from LDS ----
    const unsigned short* Kb = Ks[buf];
    short8 ka[4][2];
#pragma unroll
    for (int t4 = 0; t4 < 4; ++t4)
#pragma unroll
      for (int c = 0; c < 2; ++c)
        ka[t4][c] = *(const short8*)(Kb + (t4 * 16 + lq) * 64 + (((c * 4 + quad) ^ l3) * 8));

    // ---- S^T = K·Q^T (Q pre-scaled by SCALE*log2e) ----
    f32x4 s[4];
#pragma unroll
    for (int t4 = 0; t4 < 4; ++t4) {
      f32x4 z = (f32x4){0.f, 0.f, 0.f, 0.f};
      z = __builtin_amdgcn_mfma_f32_16x16x32_bf16(ka[t4][0], bq0, z, 0, 0, 0);
      s[t4] = __builtin_amdgcn_mfma_f32_16x16x32_bf16(ka[t4][1], bq1, z, 0, 0, 0);
    }

    // ---- p = exp2(s), diagonal mask, in-lane row-sum, in-register PV ----
    const bool diag = (kt == qt);
    const int kc0 = kt * 64 + quad * 4;
    const unsigned short* Vb = Vs[buf];
    float rs = 0.f;
    __builtin_amdgcn_s_setprio(1);
#pragma unroll
    for (int t4 = 0; t4 < 4; ++t4) {
      float p0 = EXP2(s[t4][0]), p1 = EXP2(s[t4][1]);
      float p2 = EXP2(s[t4][2]), p3 = EXP2(s[t4][3]);
      if (diag) {
        const int kc = kc0 + t4 * 16;
        if (kc + 0 > qrow) p0 = 0.f;
        if (kc + 1 > qrow) p1 = 0.f;
        if (kc + 2 > qrow) p2 = 0.f;
        if (kc + 3 > qrow) p3 = 0.f;
      }
      rs += (p0 + p1) + (p2 + p3);
      unsigned ww[2];
      ww[0] = pack_bf2(p0, p1);
      ww[1] = pack_bf2(p2, p3);
      short4b pb;
      __builtin_memcpy(&pb, ww, 8);
      const int cg = t4 * 2 + (quad >> 1);
      const int vcol = ((cg ^ l3) * 8) + (quad & 1) * 4;
#pragma unroll
      for (int nd = 0; nd < 4; ++nd) {
        short4b va4;
        __builtin_memcpy(&va4, Vb + (nd * 16 + lq) * 64 + vcol, 8);
        o_acc[nd] = __builtin_amdgcn_mfma_f32_16x16x16bf16_1k(va4, pb,
                                                              o_acc[nd], 0, 0, 0);
      }
    }
    __builtin_amdgcn_s_setprio(0);
    l_sum += rs;
  }

  // final cross-quad row-sum reduction
  l_sum += __shfl_xor(l_sum, 16);
  l_sum += __shfl_xor(l_sum, 32);

  const int b = bh >> 4, h = bh & 15;
  const float inv = 1.0f / l_sum;
  const int n = qrow >> 1, p = qrow & 1;
  unsigned short* dst = Aov + ((size_t)(b * 1024 + n)) * 2048 + (h * 2 + p) * 64;
#pragma unroll
  for (int nd = 0; nd < 4; ++nd) {
    uint2 dw;
    dw.x = pack_bf2(o_acc[nd][0] * inv, o_acc[nd][1] * inv);
    dw.y = pack_bf2(o_acc[nd][2] * inv, o_acc[nd][3] * inv);
    *(uint2*)(dst + nd * 16 + quad * 4) = dw;
  }
}

// ---------------------------------------------------------------------------
extern "C" void kernel_launch(void* const* d_in, const int* in_sizes, int n_in,
                              void* d_out, int out_size, void* d_ws, size_t ws_size,
                              hipStream_t stream) {
  (void)in_sizes; (void)n_in; (void)out_size; (void)ws_size;
  const float* x    = (const float*)d_in[0];
  const float* Wq   = (const float*)d_in[1];
  const float* Wk   = (const float*)d_in[2];
  const float* Wv   = (const float*)d_in[3];
  const float* Wo   = (const float*)d_in[4];
  const float* aq   = (const float*)d_in[5];
  const float* ak   = (const float*)d_in[6];
  const float* av   = (const float*)d_in[7];
  const float* coll = (const float*)d_in[8];
  float* out = (float*)d_out;

  char* ws = (char*)d_ws;
  const size_t MB = 1024 * 1024;
  unsigned short* Xb    = (unsigned short*)(ws);            // 4 MB  [0,4)
  unsigned short* Woeff = (unsigned short*)(ws + 4 * MB);   // 4 MB  [4,8)
  unsigned short* Weff  = (unsigned short*)(ws + 8 * MB);   // 12 MB [8,20)
  unsigned short* Qv    = (unsigned short*)(ws + 20 * MB);  // 8 MB  [20,28)
  unsigned short* Kv    = (unsigned short*)(ws + 28 * MB);  // 8 MB  [28,36)
  unsigned short* Vt    = (unsigned short*)(ws + 36 * MB);  // 8 MB  [36,44)
  // Weff dead after QKV GEMM; reuse:
  unsigned short* Aov   = (unsigned short*)(ws + 8 * MB);   // 8 MB  [8,16)

  prep_kernel<<<dim3(2240), dim3(256), 0, stream>>>(
      x, Wq, Wk, Wv, Wo, aq, ak, av, coll, Xb, Weff, Woeff);
  qkv_gemm128<<<dim3(768), dim3(256), 0, stream>>>(Xb, Weff, Qv, Kv, Vt);
  attn_kernel<<<dim3(32, 32), dim3(256), 0, stream>>>(Qv, Kv, Vt, Aov);
  gemm64p<<<dim3(512), dim3(256), 0, stream>>>(Aov, Woeff, out);
}